// Round 1
// baseline (4117.976 us; speedup 1.0000x reference)
//
#include <hip/hip_runtime.h>
#include <math.h>

#define B_    128
#define T_    100
#define TPAD  104
#define CB_   4
#define EMB_  128
#define HIDC  512
#define LAT_  256
#define NC_   1024
#define MPAD  (B_*TPAD)   // 13312 padded rows

// ---------------- zero the pad rows (t=100..103) of both conv buffers ----------------
__global__ void k_zeropad(float* __restrict__ a, float* __restrict__ b) {
  int id = blockIdx.x * 256 + threadIdx.x;     // 128*4*512 = 262144
  int c = id & 511;
  int r = id >> 9;                              // 0..511
  int bb = r >> 2, t = 100 + (r & 3);
  int off = (bb * TPAD + t) * 512 + c;
  a[off] = 0.f;
  b[off] = 0.f;
}

// ---------------- embedding gather: x[b][t][cb*128+e] = emb[tok[b,t,cb]][e] ----------------
__global__ void k_embed(const int* __restrict__ tok, const float* __restrict__ emb,
                        float* __restrict__ x) {
  int id = blockIdx.x * 256 + threadIdx.x;      // B*T*512 = 6,553,600 exact
  int c = id & 511;
  int bt = id >> 9;
  int t = bt % T_, b = bt / T_;
  int cb = c >> 7, e = c & 127;
  int tk = tok[(b * T_ + t) * CB_ + cb];
  x[(b * TPAD + t) * 512 + c] = emb[tk * EMB_ + e];
}

// ---------------- 3-tap conv as tiled GEMM: Y[r][o] = relu(bias + sum_{i,k} W[o,i,k] X[r+k-1][i]) ----------------
__global__ __launch_bounds__(256) void k_conv3(const float* __restrict__ X,
                                               const float* __restrict__ W,
                                               const float* __restrict__ bias,
                                               float* __restrict__ Y) {
  __shared__ float As[32][68];      // [kk][row 0..65]
  __shared__ float Ws[3][32][68];   // [tap][kk][o 0..63]
  int r0 = blockIdx.x * 64;
  int o0 = blockIdx.y * 64;
  int tid = threadIdx.x;
  int tc = tid & 15, tr = tid >> 4;
  float acc[4][4] = {};
  for (int kc = 0; kc < 512; kc += 32) {
    __syncthreads();
    // stage A rows r0-1 .. r0+64 (66 rows) x 32 k
    #pragma unroll
    for (int j = 0; j < 9; ++j) {
      int idx = tid + 256 * j;
      if (idx < 2112) {
        int row = idx >> 5, kk = idx & 31;
        int r = r0 - 1 + row;
        float v = 0.f;
        if (r >= 0 && r < MPAD) v = X[r * 512 + kc + kk];
        As[kk][row] = v;
      }
    }
    // stage W: 3*32*64 = 6144 elements
    #pragma unroll
    for (int j = 0; j < 24; ++j) {
      int idx = tid + 256 * j;
      int o = idx / 96;
      int rem = idx % 96;            // = (kk,k)
      int kk = rem / 3, k = rem % 3;
      Ws[k][kk][o] = W[(o0 + o) * 1536 + kc * 3 + rem];
    }
    __syncthreads();
    #pragma unroll 4
    for (int kk = 0; kk < 32; ++kk) {
      const float* ap = &As[kk][tr * 4];
      float4 alo = *(const float4*)ap;
      float2 ahi = *(const float2*)(ap + 4);
      float a[6] = {alo.x, alo.y, alo.z, alo.w, ahi.x, ahi.y};
      #pragma unroll
      for (int k = 0; k < 3; ++k) {
        float4 bv = *(const float4*)&Ws[k][kk][tc * 4];
        #pragma unroll
        for (int rr = 0; rr < 4; ++rr) {
          float av = a[rr + k];
          acc[rr][0] = fmaf(av, bv.x, acc[rr][0]);
          acc[rr][1] = fmaf(av, bv.y, acc[rr][1]);
          acc[rr][2] = fmaf(av, bv.z, acc[rr][2]);
          acc[rr][3] = fmaf(av, bv.w, acc[rr][3]);
        }
      }
    }
  }
  #pragma unroll
  for (int rr = 0; rr < 4; ++rr) {
    int r = r0 + tr * 4 + rr;
    int t = r % TPAD;
    if (t < T_) {
      float4 v;
      int o = o0 + tc * 4;
      v.x = fmaxf(acc[rr][0] + bias[o + 0], 0.f);
      v.y = fmaxf(acc[rr][1] + bias[o + 1], 0.f);
      v.z = fmaxf(acc[rr][2] + bias[o + 2], 0.f);
      v.w = fmaxf(acc[rr][3] + bias[o + 3], 0.f);
      *(float4*)&Y[r * 512 + o] = v;
    }
  }
}

// ---------------- adaptive avg pool: every bin is 13 taps, weight 1/13 ----------------
__global__ void k_pool(const float* __restrict__ Y, float* __restrict__ pooled) {
  int id = blockIdx.x * 256 + threadIdx.x;   // 1024*512 exact
  int c = id & 511;
  int row = id >> 9;                          // b*8+p
  int p = row & 7, b = row >> 3;
  int t0 = (p * 25) >> 1;                     // 0,12,25,37,50,62,75,87
  const float* src = Y + (b * TPAD + t0) * 512 + c;
  float s = 0.f;
  #pragma unroll
  for (int j = 0; j < 13; ++j) s += src[j * 512];
  pooled[id] = s * (1.f / 13.f);
}

// ---------------- generic tiled GEMM: C[M][N] = act(A[M][K] @ B[N][K]^T + bias) ----------------
__global__ __launch_bounds__(256) void k_gemm_abt(const float* __restrict__ A,
                                                  const float* __restrict__ Bm,
                                                  float* __restrict__ C,
                                                  int K, int N,
                                                  const float* __restrict__ bias,
                                                  int relu) {
  __shared__ float As[32][68];
  __shared__ float Bs[32][68];
  int r0 = blockIdx.x * 64, c0 = blockIdx.y * 64;
  int tid = threadIdx.x, tc = tid & 15, tr = tid >> 4;
  float acc[4][4] = {};
  for (int kc = 0; kc < K; kc += 32) {
    __syncthreads();
    #pragma unroll
    for (int j = 0; j < 8; ++j) {
      int idx = tid + 256 * j;
      int row = idx >> 5, kk = idx & 31;
      As[kk][row] = A[(r0 + row) * K + kc + kk];
      Bs[kk][row] = Bm[(c0 + row) * K + kc + kk];
    }
    __syncthreads();
    #pragma unroll 8
    for (int kk = 0; kk < 32; ++kk) {
      float4 a = *(const float4*)&As[kk][tr * 4];
      float4 b = *(const float4*)&Bs[kk][tc * 4];
      acc[0][0] = fmaf(a.x, b.x, acc[0][0]);
      acc[0][1] = fmaf(a.x, b.y, acc[0][1]);
      acc[0][2] = fmaf(a.x, b.z, acc[0][2]);
      acc[0][3] = fmaf(a.x, b.w, acc[0][3]);
      acc[1][0] = fmaf(a.y, b.x, acc[1][0]);
      acc[1][1] = fmaf(a.y, b.y, acc[1][1]);
      acc[1][2] = fmaf(a.y, b.z, acc[1][2]);
      acc[1][3] = fmaf(a.y, b.w, acc[1][3]);
      acc[2][0] = fmaf(a.z, b.x, acc[2][0]);
      acc[2][1] = fmaf(a.z, b.y, acc[2][1]);
      acc[2][2] = fmaf(a.z, b.z, acc[2][2]);
      acc[2][3] = fmaf(a.z, b.w, acc[2][3]);
      acc[3][0] = fmaf(a.w, b.x, acc[3][0]);
      acc[3][1] = fmaf(a.w, b.y, acc[3][1]);
      acc[3][2] = fmaf(a.w, b.z, acc[3][2]);
      acc[3][3] = fmaf(a.w, b.w, acc[3][3]);
    }
  }
  #pragma unroll
  for (int rr = 0; rr < 4; ++rr) {
    int r = r0 + tr * 4 + rr;
    int c = c0 + tc * 4;
    float4 v;
    v.x = acc[rr][0]; v.y = acc[rr][1]; v.z = acc[rr][2]; v.w = acc[rr][3];
    if (bias) { v.x += bias[c]; v.y += bias[c + 1]; v.z += bias[c + 2]; v.w += bias[c + 3]; }
    if (relu) { v.x = fmaxf(v.x, 0.f); v.y = fmaxf(v.y, 0.f); v.z = fmaxf(v.z, 0.f); v.w = fmaxf(v.w, 0.f); }
    *(float4*)&C[r * N + c] = v;
  }
}

// ---------------- codebook squared norms ----------------
__global__ void k_cbsq(const float* __restrict__ cb, float* __restrict__ cbsq) {
  __shared__ float sm[256];
  int k = blockIdx.x, tid = threadIdx.x;
  float v = cb[k * 256 + tid];
  sm[tid] = v * v;
  __syncthreads();
  for (int off = 128; off; off >>= 1) { if (tid < off) sm[tid] += sm[tid + off]; __syncthreads(); }
  if (tid == 0) cbsq[k] = sm[0];
}

// ---------------- VQ argmin + z_q gather into z_all + commit partial ----------------
__global__ __launch_bounds__(256) void k_vq(const float* __restrict__ dot,
                                            const float* __restrict__ cbsq,
                                            const float* __restrict__ ze,
                                            const float* __restrict__ cb,
                                            float* __restrict__ zall,
                                            float* __restrict__ commit_part, int s) {
  __shared__ float sv[256];
  __shared__ int si[256];
  int row = blockIdx.x, tid = threadIdx.x;
  float best = 3.4e38f; int bi = 0;
  #pragma unroll
  for (int j = 0; j < 4; ++j) {
    int k = tid * 4 + j;
    float d = cbsq[k] - 2.f * dot[row * 1024 + k];
    if (d < best) { best = d; bi = k; }
  }
  sv[tid] = best; si[tid] = bi;
  __syncthreads();
  for (int off = 128; off; off >>= 1) {
    if (tid < off) {
      float o = sv[tid + off]; int oi = si[tid + off];
      if (o < sv[tid] || (o == sv[tid] && oi < si[tid])) { sv[tid] = o; si[tid] = oi; }
    }
    __syncthreads();
  }
  int ks = si[0];
  float zq = cb[ks * 256 + tid];
  float zev = ze[row * 256 + tid];
  int b = row >> 3, p = row & 7;
  zall[b * 6144 + s * 2048 + p * 256 + tid] = zq;
  float d = zev - zq;
  __syncthreads();
  sv[tid] = d * d;
  __syncthreads();
  for (int off = 128; off; off >>= 1) { if (tid < off) sv[tid] += sv[tid + off]; __syncthreads(); }
  if (tid == 0) commit_part[s * 1024 + row] = sv[0];
}

// ---------------- deconv1 collapsed tap-sum weights: S[cls][o][i] ----------------
// w1[o,i,k] = d1w[i,o,2-k]; t=0 uses taps k=1,2 -> d1w[.,.,{1,0}]; mid all; t=99 -> d1w[.,.,{2,1}]
__global__ void k_buildS(const float* __restrict__ d1w, float* __restrict__ S) {
  int id = blockIdx.x * 256 + threadIdx.x;   // 3*512*512 exact
  int i = id & 511;
  int o = (id >> 9) & 511;
  int cls = id >> 18;
  const float* w = d1w + (i * 512 + o) * 3;
  float v;
  if (cls == 0)      v = w[0] + w[1];
  else if (cls == 1) v = w[0] + w[1] + w[2];
  else               v = w[1] + w[2];
  S[(cls * 512 + o) * 512 + i] = v;
}

// ---------------- transpose d2w [512][4096] -> [4096][512] ----------------
__global__ void k_transpose(const float* __restrict__ src, float* __restrict__ dst) {
  __shared__ float tile[32][33];
  int bx = blockIdx.x, by = blockIdx.y;
  int tx = threadIdx.x & 31, ty = threadIdx.x >> 5;
  #pragma unroll
  for (int j = 0; j < 32; j += 8)
    tile[ty + j][tx] = src[(by * 32 + ty + j) * 4096 + bx * 32 + tx];
  __syncthreads();
  #pragma unroll
  for (int j = 0; j < 32; j += 8)
    dst[(bx * 32 + ty + j) * 512 + by * 32 + tx] = tile[tx][ty + j];
}

// ---------------- logsumexp over each 1024-vocab row ----------------
__global__ __launch_bounds__(256) void k_lse(const float* __restrict__ logits,
                                             float* __restrict__ lse) {
  __shared__ float sm[256];
  int blk = blockIdx.x;                       // cls*512 + b*4 + cb
  int cb_i = blk & 3, b = (blk >> 2) & 127, cls = blk >> 9;
  const float* rp = logits + (cls * 128 + b) * 4096 + cb_i * 1024;
  int tid = threadIdx.x;
  float v0 = rp[tid], v1 = rp[tid + 256], v2 = rp[tid + 512], v3 = rp[tid + 768];
  float m = fmaxf(fmaxf(v0, v1), fmaxf(v2, v3));
  sm[tid] = m; __syncthreads();
  for (int off = 128; off; off >>= 1) { if (tid < off) sm[tid] = fmaxf(sm[tid], sm[tid + off]); __syncthreads(); }
  float gm = sm[0]; __syncthreads();
  float e = expf(v0 - gm) + expf(v1 - gm) + expf(v2 - gm) + expf(v3 - gm);
  sm[tid] = e; __syncthreads();
  for (int off = 128; off; off >>= 1) { if (tid < off) sm[tid] += sm[tid + off]; __syncthreads(); }
  if (tid == 0) lse[blk] = gm + logf(sm[0]);
}

// ---------------- recon nll partial sums ----------------
__global__ void k_recon(const int* __restrict__ tok, const float* __restrict__ logits,
                        const float* __restrict__ lse, float* __restrict__ part) {
  __shared__ float sm[256];
  int id = blockIdx.x * 256 + threadIdx.x;    // 51200 exact -> 200 blocks
  int cb_i = id & 3;
  int t = (id >> 2) % 100;
  int b = id / 400;
  int tk = tok[id];
  int cls = (t == 0) ? 0 : ((t == 99) ? 2 : 1);
  float val = lse[cls * 512 + b * 4 + cb_i]
            - logits[(cls * 128 + b) * 4096 + cb_i * 1024 + tk];
  int tid = threadIdx.x;
  sm[tid] = val; __syncthreads();
  for (int off = 128; off; off >>= 1) { if (tid < off) sm[tid] += sm[tid + off]; __syncthreads(); }
  if (tid == 0) part[blockIdx.x] = sm[0];
}

// ---------------- final: total = recon_mean + 0.1 * commit_mean_sum ----------------
__global__ void k_final(const float* __restrict__ rpart, const float* __restrict__ cpart,
                        float* __restrict__ out) {
  __shared__ float sm[256];
  __shared__ float rs;
  int tid = threadIdx.x;
  float r = (tid < 200) ? rpart[tid] : 0.f;
  sm[tid] = r; __syncthreads();
  for (int off = 128; off; off >>= 1) { if (tid < off) sm[tid] += sm[tid + off]; __syncthreads(); }
  if (tid == 0) rs = sm[0];
  __syncthreads();
  float c = 0.f;
  #pragma unroll
  for (int j = 0; j < 12; ++j) c += cpart[tid + 256 * j];
  sm[tid] = c; __syncthreads();
  for (int off = 128; off; off >>= 1) { if (tid < off) sm[tid] += sm[tid + off]; __syncthreads(); }
  if (tid == 0) out[0] = rs / 51200.f + 0.1f * (sm[0] / 262144.f);
}

extern "C" void kernel_launch(void* const* d_in, const int* in_sizes, int n_in,
                              void* d_out, int out_size, void* d_ws, size_t ws_size,
                              hipStream_t stream) {
  const int*   tok_prev = (const int*)d_in[0];
  const int*   tok_curr = (const int*)d_in[1];
  const int*   tok_next = (const int*)d_in[2];
  const float* emb  = (const float*)d_in[3];
  const float* c1w  = (const float*)d_in[4];
  const float* c1b  = (const float*)d_in[5];
  const float* c2w  = (const float*)d_in[6];
  const float* c2b  = (const float*)d_in[7];
  const float* c3w  = (const float*)d_in[8];
  const float* c3b  = (const float*)d_in[9];
  const float* cbk  = (const float*)d_in[10];
  const float* fc1w = (const float*)d_in[11];
  const float* fc1b = (const float*)d_in[12];
  const float* fc2w = (const float*)d_in[13];
  const float* fc2b = (const float*)d_in[14];
  const float* d1w  = (const float*)d_in[15];
  const float* d1b  = (const float*)d_in[16];
  const float* d2w  = (const float*)d_in[17];
  const float* d2b  = (const float*)d_in[18];

  float* ws = (float*)d_ws;
  float* bufA   = ws;                       // 13312*512 = 6,815,744
  float* bufB   = bufA   + 6815744;         // 6,815,744
  float* pooled = bufB   + 6815744;         // 1024*512  =   524,288
  float* ze     = pooled + 524288;          // 1024*256  =   262,144
  float* dotb   = ze     + 262144;          // 1024*1024 = 1,048,576
  float* cbsq   = dotb   + 1048576;         //               1,024
  float* zall   = cbsq   + 1024;            // 128*6144  =   786,432
  float* cpart  = zall   + 786432;          // 3*1024    =     3,072
  float* h1     = cpart  + 3072;            // 128*512   =    65,536
  float* h2     = h1     + 65536;           //                65,536
  float* S      = h2     + 65536;           // 3*512*512 =   786,432
  float* h2c    = S      + 786432;          // 3*128*512 =   196,608
  float* d2wT   = h2c    + 196608;          // 4096*512  = 2,097,152
  float* logitsb= d2wT   + 2097152;         // 384*4096  = 1,572,864
  float* lseb   = logitsb+ 1572864;         //                1,536
  float* rpart  = lseb   + 1536;            //                  256
  // total ~21.0M floats ~84.2 MB

  k_zeropad  <<<1024, 256, 0, stream>>>(bufA, bufB);
  k_buildS   <<<3072, 256, 0, stream>>>(d1w, S);
  k_transpose<<<dim3(128, 16), 256, 0, stream>>>(d2w, d2wT);
  k_cbsq     <<<1024, 256, 0, stream>>>(cbk, cbsq);

  const int* toks[3] = {tok_prev, tok_curr, tok_next};
  for (int s = 0; s < 3; ++s) {
    k_embed   <<<25600, 256, 0, stream>>>(toks[s], emb, bufA);
    k_conv3   <<<dim3(208, 8), 256, 0, stream>>>(bufA, c1w, c1b, bufB);
    k_conv3   <<<dim3(208, 8), 256, 0, stream>>>(bufB, c2w, c2b, bufA);
    k_pool    <<<2048, 256, 0, stream>>>(bufA, pooled);
    k_gemm_abt<<<dim3(16, 4),  256, 0, stream>>>(pooled, c3w, ze, 512, 256, c3b, 0);
    k_gemm_abt<<<dim3(16, 16), 256, 0, stream>>>(ze, cbk, dotb, 256, 1024, nullptr, 0);
    k_vq      <<<1024, 256, 0, stream>>>(dotb, cbsq, ze, cbk, zall, cpart, s);
  }

  k_gemm_abt<<<dim3(2, 8), 256, 0, stream>>>(zall, fc1w, h1, 6144, 512, fc1b, 1);
  k_gemm_abt<<<dim3(2, 8), 256, 0, stream>>>(h1, fc2w, h2, 512, 512, fc2b, 1);
  for (int cls = 0; cls < 3; ++cls)
    k_gemm_abt<<<dim3(2, 8), 256, 0, stream>>>(h2, S + cls * 262144, h2c + cls * 65536,
                                               512, 512, d1b, 1);
  k_gemm_abt<<<dim3(6, 64), 256, 0, stream>>>(h2c, d2wT, logitsb, 512, 4096, d2b, 0);

  k_lse  <<<1536, 256, 0, stream>>>(logitsb, lseb);
  k_recon<<<200, 256, 0, stream>>>(tok_curr, logitsb, lseb, rpart);
  k_final<<<1, 256, 0, stream>>>(rpart, cpart, (float*)d_out);
}

// Round 2
// 2051.070 us; speedup vs baseline: 2.0077x; 2.0077x over previous
//
#include <hip/hip_runtime.h>
#include <math.h>

#define B_    128
#define T_    100
#define TPAD  104
#define CB_   4
#define EMB_  128
#define HIDC  512
#define LAT_  256
#define NC_   1024
#define NROW  39936          // 3*128*104 padded rows (all 3 segments)

typedef __attribute__((ext_vector_type(8))) short short8;
typedef __attribute__((ext_vector_type(4))) float f32x4;

__device__ __forceinline__ short f2bf(float x) {
  unsigned u = __builtin_bit_cast(unsigned, x);
  u += 0x7fffu + ((u >> 16) & 1u);
  return (short)(u >> 16);
}
__device__ __forceinline__ float bf2f(short s) {
  unsigned u = ((unsigned)(unsigned short)s) << 16;
  return __builtin_bit_cast(float, u);
}

// ---------------- zero guard rows (raw row 0 and NROW+1) of both bf16 buffers ----------------
__global__ void k_guard(short* __restrict__ a, short* __restrict__ b) {
  int id = blockIdx.x * 256 + threadIdx.x;      // 2048
  short* buf = (id >> 10) ? b : a;
  int rem = id & 1023;
  int row = rem >> 9, c = rem & 511;
  long off = row ? ((long)(NROW + 1) * 512 + c) : c;
  buf[off] = 0;
}

// ---------------- convert both conv weights to bf16 layout [tap][o][i] ----------------
__global__ void k_wconv(const float* __restrict__ w1, const float* __restrict__ w2,
                        short* __restrict__ o1, short* __restrict__ o2) {
  int id = blockIdx.x * 256 + threadIdx.x;      // 2*786432 exact
  const float* w = (id < 786432) ? w1 : w2;
  short* o = (id < 786432) ? o1 : o2;
  int local = id & 786431;
  int i = local & 511;
  int oo = (local >> 9) & 511;
  int tap = local >> 18;
  o[local] = f2bf(w[oo * 1536 + i * 3 + tap]);
}

// ---------------- embedding gather (all 3 segs) -> bf16 padded buffer ----------------
__global__ void k_embed(const int* __restrict__ t0, const int* __restrict__ t1,
                        const int* __restrict__ t2, const float* __restrict__ emb,
                        short* __restrict__ x) {   // x = raw base (guard at row 0)
  int id = blockIdx.x * 256 + threadIdx.x;      // NROW*512 = 20,447,232 exact
  int c = id & 511;
  int row = id >> 9;
  int t = row % TPAD;
  int sb = row / TPAD;
  int b = sb & 127, s = sb >> 7;
  short v = 0;
  if (t < T_) {
    const int* tok = (s == 0) ? t0 : (s == 1) ? t1 : t2;
    int tk = tok[(b * T_ + t) * CB_ + (c >> 7)];
    v = f2bf(emb[tk * EMB_ + (c & 127)]);
  }
  x[(long)(row + 1) * 512 + c] = v;
}

// ---------------- 3-tap conv via bf16 MFMA 16x16x32 ----------------
// X: bf16 rows, valid indices [-1 .. NROW]; Wb: [3][512(o)][512(i)] bf16; Y: bf16 rows [0..NROW)
#define MFMA16(a, b, c) __builtin_amdgcn_mfma_f32_16x16x32_bf16(a, b, c, 0, 0, 0)
#define SWZ(row, slot) (((slot) + ((row) >> 1)) & 3)

__global__ __launch_bounds__(256) void k_conv3_mfma(const short* __restrict__ X,
                                                    const short* __restrict__ Wb,
                                                    const float* __restrict__ bias,
                                                    short* __restrict__ Y) {
  __shared__ short8 sA[130][4];
  __shared__ short8 sB[3][128][4];
  int r0 = blockIdx.x * 128;
  int o0 = blockIdx.y * 128;
  int tid = threadIdx.x;
  int lane = tid & 63, wid = tid >> 6;
  int wm = wid >> 1, wn = wid & 1;
  int ls = lane >> 4, lr = lane & 15;
  f32x4 acc[4][4] = {};
  for (int kc = 0; kc < 512; kc += 32) {
    __syncthreads();
    #pragma unroll
    for (int j = 0; j < 3; ++j) {
      int idx = tid + 256 * j;
      if (idx < 520) {
        int row = idx >> 2, slot = idx & 3;
        const short8* gp = (const short8*)(X + (long)(r0 - 1 + row) * 512 + kc);
        sA[row][SWZ(row, slot)] = gp[slot];
      }
    }
    #pragma unroll
    for (int j = 0; j < 6; ++j) {
      int idx = tid + 256 * j;
      int tap = idx >> 9, rem = idx & 511;
      int row = rem >> 2, slot = rem & 3;
      const short8* gp = (const short8*)(Wb + ((tap * 512) + o0 + row) * 512 + kc);
      sB[tap][row][SWZ(row, slot)] = gp[slot];
    }
    __syncthreads();
    #pragma unroll
    for (int tap = 0; tap < 3; ++tap) {
      short8 a[4], b[4];
      #pragma unroll
      for (int m = 0; m < 4; ++m) {
        int row = wm * 64 + m * 16 + lr + tap;
        a[m] = sA[row][SWZ(row, ls)];
      }
      #pragma unroll
      for (int n = 0; n < 4; ++n) {
        int row = wn * 64 + n * 16 + lr;
        b[n] = sB[tap][row][SWZ(row, ls)];
      }
      #pragma unroll
      for (int m = 0; m < 4; ++m)
        #pragma unroll
        for (int n = 0; n < 4; ++n)
          acc[m][n] = MFMA16(a[m], b[n], acc[m][n]);
    }
  }
  #pragma unroll
  for (int m = 0; m < 4; ++m) {
    #pragma unroll
    for (int n = 0; n < 4; ++n) {
      int col = o0 + wn * 64 + n * 16 + lr;
      float bv = bias[col];
      #pragma unroll
      for (int j = 0; j < 4; ++j) {
        int r = r0 + wm * 64 + m * 16 + ls * 4 + j;
        int t = r % TPAD;
        float v = (t < T_) ? fmaxf(acc[m][n][j] + bv, 0.f) : 0.f;
        Y[(long)r * 512 + col] = f2bf(v);
      }
    }
  }
}

// ---------------- adaptive pool: 13 taps, 1/13 each; bf16 in, f32 out ----------------
__global__ void k_pool(const short* __restrict__ Xg, float* __restrict__ pooled) {
  int id = blockIdx.x * 256 + threadIdx.x;   // 3072*64 = 196608 exact
  int row = id >> 6, cg = id & 63;
  int s = row >> 10, bp = row & 1023;
  int b = bp >> 3, p = bp & 7;
  int t0 = (p * 25) >> 1;
  const short8* src = (const short8*)(Xg + (long)((s * 128 + b) * TPAD + t0) * 512) + cg;
  float acc[8] = {};
  #pragma unroll
  for (int j = 0; j < 13; ++j) {
    short8 v = src[j * 64];
    #pragma unroll
    for (int k = 0; k < 8; ++k) acc[k] += bf2f(v[k]);
  }
  float4 lo, hi;
  lo.x = acc[0] * (1.f / 13.f); lo.y = acc[1] * (1.f / 13.f);
  lo.z = acc[2] * (1.f / 13.f); lo.w = acc[3] * (1.f / 13.f);
  hi.x = acc[4] * (1.f / 13.f); hi.y = acc[5] * (1.f / 13.f);
  hi.z = acc[6] * (1.f / 13.f); hi.w = acc[7] * (1.f / 13.f);
  *(float4*)&pooled[(long)row * 512 + cg * 8] = lo;
  *(float4*)&pooled[(long)row * 512 + cg * 8 + 4] = hi;
}

// ---------------- generic fp32 tiled GEMM: C = act(A[M][K] @ B[N][K]^T + bias) ----------------
__global__ __launch_bounds__(256) void k_gemm_abt(const float* __restrict__ A,
                                                  const float* __restrict__ Bm,
                                                  float* __restrict__ C,
                                                  int K, int N,
                                                  const float* __restrict__ bias,
                                                  int relu) {
  __shared__ float As[32][68];
  __shared__ float Bs[32][68];
  int r0 = blockIdx.x * 64, c0 = blockIdx.y * 64;
  int tid = threadIdx.x, tc = tid & 15, tr = tid >> 4;
  float acc[4][4] = {};
  for (int kc = 0; kc < K; kc += 32) {
    __syncthreads();
    #pragma unroll
    for (int j = 0; j < 8; ++j) {
      int idx = tid + 256 * j;
      int row = idx >> 5, kk = idx & 31;
      As[kk][row] = A[(r0 + row) * K + kc + kk];
      Bs[kk][row] = Bm[(c0 + row) * K + kc + kk];
    }
    __syncthreads();
    #pragma unroll 8
    for (int kk = 0; kk < 32; ++kk) {
      float4 a = *(const float4*)&As[kk][tr * 4];
      float4 b = *(const float4*)&Bs[kk][tc * 4];
      acc[0][0] = fmaf(a.x, b.x, acc[0][0]);
      acc[0][1] = fmaf(a.x, b.y, acc[0][1]);
      acc[0][2] = fmaf(a.x, b.z, acc[0][2]);
      acc[0][3] = fmaf(a.x, b.w, acc[0][3]);
      acc[1][0] = fmaf(a.y, b.x, acc[1][0]);
      acc[1][1] = fmaf(a.y, b.y, acc[1][1]);
      acc[1][2] = fmaf(a.y, b.z, acc[1][2]);
      acc[1][3] = fmaf(a.y, b.w, acc[1][3]);
      acc[2][0] = fmaf(a.z, b.x, acc[2][0]);
      acc[2][1] = fmaf(a.z, b.y, acc[2][1]);
      acc[2][2] = fmaf(a.z, b.z, acc[2][2]);
      acc[2][3] = fmaf(a.z, b.w, acc[2][3]);
      acc[3][0] = fmaf(a.w, b.x, acc[3][0]);
      acc[3][1] = fmaf(a.w, b.y, acc[3][1]);
      acc[3][2] = fmaf(a.w, b.z, acc[3][2]);
      acc[3][3] = fmaf(a.w, b.w, acc[3][3]);
    }
  }
  #pragma unroll
  for (int rr = 0; rr < 4; ++rr) {
    int r = r0 + tr * 4 + rr;
    int c = c0 + tc * 4;
    float4 v;
    v.x = acc[rr][0]; v.y = acc[rr][1]; v.z = acc[rr][2]; v.w = acc[rr][3];
    if (bias) { v.x += bias[c]; v.y += bias[c + 1]; v.z += bias[c + 2]; v.w += bias[c + 3]; }
    if (relu) { v.x = fmaxf(v.x, 0.f); v.y = fmaxf(v.y, 0.f); v.z = fmaxf(v.z, 0.f); v.w = fmaxf(v.w, 0.f); }
    *(float4*)&C[r * N + c] = v;
  }
}

// ---------------- codebook squared norms ----------------
__global__ void k_cbsq(const float* __restrict__ cb, float* __restrict__ cbsq) {
  __shared__ float sm[256];
  int k = blockIdx.x, tid = threadIdx.x;
  float v = cb[k * 256 + tid];
  sm[tid] = v * v;
  __syncthreads();
  for (int off = 128; off; off >>= 1) { if (tid < off) sm[tid] += sm[tid + off]; __syncthreads(); }
  if (tid == 0) cbsq[k] = sm[0];
}

// ---------------- VQ argmin + gather + commit partial (all 3 segs) ----------------
__global__ __launch_bounds__(256) void k_vq(const float* __restrict__ dot,
                                            const float* __restrict__ cbsq,
                                            const float* __restrict__ ze,
                                            const float* __restrict__ cb,
                                            float* __restrict__ zall,
                                            float* __restrict__ commit_part) {
  __shared__ float sv[256];
  __shared__ int si[256];
  int row = blockIdx.x, tid = threadIdx.x;   // row = s*1024 + b*8 + p
  float best = 3.4e38f; int bi = 0;
  #pragma unroll
  for (int j = 0; j < 4; ++j) {
    int k = tid * 4 + j;
    float d = cbsq[k] - 2.f * dot[(long)row * 1024 + k];
    if (d < best) { best = d; bi = k; }
  }
  sv[tid] = best; si[tid] = bi;
  __syncthreads();
  for (int off = 128; off; off >>= 1) {
    if (tid < off) {
      float o = sv[tid + off]; int oi = si[tid + off];
      if (o < sv[tid] || (o == sv[tid] && oi < si[tid])) { sv[tid] = o; si[tid] = oi; }
    }
    __syncthreads();
  }
  int ks = si[0];
  float zq = cb[ks * 256 + tid];
  float zev = ze[(long)row * 256 + tid];
  int s = row >> 10, bp = row & 1023;
  int b = bp >> 3, p = bp & 7;
  zall[b * 6144 + s * 2048 + p * 256 + tid] = zq;
  float d = zev - zq;
  __syncthreads();
  sv[tid] = d * d;
  __syncthreads();
  for (int off = 128; off; off >>= 1) { if (tid < off) sv[tid] += sv[tid + off]; __syncthreads(); }
  if (tid == 0) commit_part[row] = sv[0];
}

// ---------------- deconv1 collapsed tap-sum weights: S[cls][o][i] ----------------
__global__ void k_buildS(const float* __restrict__ d1w, float* __restrict__ S) {
  int id = blockIdx.x * 256 + threadIdx.x;   // 3*512*512 exact
  int i = id & 511;
  int o = (id >> 9) & 511;
  int cls = id >> 18;
  const float* w = d1w + (i * 512 + o) * 3;
  float v;
  if (cls == 0)      v = w[0] + w[1];
  else if (cls == 1) v = w[0] + w[1] + w[2];
  else               v = w[1] + w[2];
  S[(cls * 512 + o) * 512 + i] = v;
}

// ---------------- transpose d2w [512][4096] -> [4096][512] ----------------
__global__ void k_transpose(const float* __restrict__ src, float* __restrict__ dst) {
  __shared__ float tile[32][33];
  int bx = blockIdx.x, by = blockIdx.y;
  int tx = threadIdx.x & 31, ty = threadIdx.x >> 5;
  #pragma unroll
  for (int j = 0; j < 32; j += 8)
    tile[ty + j][tx] = src[(by * 32 + ty + j) * 4096 + bx * 32 + tx];
  __syncthreads();
  #pragma unroll
  for (int j = 0; j < 32; j += 8)
    dst[(bx * 32 + ty + j) * 512 + by * 32 + tx] = tile[tx][ty + j];
}

// ---------------- logsumexp over each 1024-vocab row ----------------
__global__ __launch_bounds__(256) void k_lse(const float* __restrict__ logits,
                                             float* __restrict__ lse) {
  __shared__ float sm[256];
  int blk = blockIdx.x;                       // cls*512 + b*4 + cb
  int cb_i = blk & 3, b = (blk >> 2) & 127, cls = blk >> 9;
  const float* rp = logits + (cls * 128 + b) * 4096 + cb_i * 1024;
  int tid = threadIdx.x;
  float v0 = rp[tid], v1 = rp[tid + 256], v2 = rp[tid + 512], v3 = rp[tid + 768];
  float m = fmaxf(fmaxf(v0, v1), fmaxf(v2, v3));
  sm[tid] = m; __syncthreads();
  for (int off = 128; off; off >>= 1) { if (tid < off) sm[tid] = fmaxf(sm[tid], sm[tid + off]); __syncthreads(); }
  float gm = sm[0]; __syncthreads();
  float e = expf(v0 - gm) + expf(v1 - gm) + expf(v2 - gm) + expf(v3 - gm);
  sm[tid] = e; __syncthreads();
  for (int off = 128; off; off >>= 1) { if (tid < off) sm[tid] += sm[tid + off]; __syncthreads(); }
  if (tid == 0) lse[blk] = gm + logf(sm[0]);
}

// ---------------- recon nll partial sums ----------------
__global__ void k_recon(const int* __restrict__ tok, const float* __restrict__ logits,
                        const float* __restrict__ lse, float* __restrict__ part) {
  __shared__ float sm[256];
  int id = blockIdx.x * 256 + threadIdx.x;    // 51200 exact
  int cb_i = id & 3;
  int t = (id >> 2) % 100;
  int b = id / 400;
  int tk = tok[id];
  int cls = (t == 0) ? 0 : ((t == 99) ? 2 : 1);
  float val = lse[cls * 512 + b * 4 + cb_i]
            - logits[(cls * 128 + b) * 4096 + cb_i * 1024 + tk];
  int tid = threadIdx.x;
  sm[tid] = val; __syncthreads();
  for (int off = 128; off; off >>= 1) { if (tid < off) sm[tid] += sm[tid + off]; __syncthreads(); }
  if (tid == 0) part[blockIdx.x] = sm[0];
}

// ---------------- final: total = recon_mean + 0.1 * commit_mean_sum ----------------
__global__ void k_final(const float* __restrict__ rpart, const float* __restrict__ cpart,
                        float* __restrict__ out) {
  __shared__ float sm[256];
  __shared__ float rs;
  int tid = threadIdx.x;
  float r = (tid < 200) ? rpart[tid] : 0.f;
  sm[tid] = r; __syncthreads();
  for (int off = 128; off; off >>= 1) { if (tid < off) sm[tid] += sm[tid + off]; __syncthreads(); }
  if (tid == 0) rs = sm[0];
  __syncthreads();
  float c = 0.f;
  #pragma unroll
  for (int j = 0; j < 12; ++j) c += cpart[tid + 256 * j];
  sm[tid] = c; __syncthreads();
  for (int off = 128; off; off >>= 1) { if (tid < off) sm[tid] += sm[tid + off]; __syncthreads(); }
  if (tid == 0) out[0] = rs / 51200.f + 0.1f * (sm[0] / 262144.f);
}

extern "C" void kernel_launch(void* const* d_in, const int* in_sizes, int n_in,
                              void* d_out, int out_size, void* d_ws, size_t ws_size,
                              hipStream_t stream) {
  const int*   tok_prev = (const int*)d_in[0];
  const int*   tok_curr = (const int*)d_in[1];
  const int*   tok_next = (const int*)d_in[2];
  const float* emb  = (const float*)d_in[3];
  const float* c1w  = (const float*)d_in[4];
  const float* c1b  = (const float*)d_in[5];
  const float* c2w  = (const float*)d_in[6];
  const float* c2b  = (const float*)d_in[7];
  const float* c3w  = (const float*)d_in[8];
  const float* c3b  = (const float*)d_in[9];
  const float* cbk  = (const float*)d_in[10];
  const float* fc1w = (const float*)d_in[11];
  const float* fc1b = (const float*)d_in[12];
  const float* fc2w = (const float*)d_in[13];
  const float* fc2b = (const float*)d_in[14];
  const float* d1w  = (const float*)d_in[15];
  const float* d1b  = (const float*)d_in[16];
  const float* d2w  = (const float*)d_in[17];
  const float* d2b  = (const float*)d_in[18];

  // ---- workspace layout (f32 word offsets) ----
  float* ws = (float*)d_ws;
  // bf16 buffers: (NROW+2) rows x 512 shorts = 20,448,256 shorts = 10,224,128 words each
  short* XbS = (short*)ws;                          // raw base, guard at row0
  short* YbS = (short*)(ws + 10224128);
  float* fp  = ws + 2 * 10224128;                   // f32 region
  short* Wb1 = (short*)fp;                          //  786,432 shorts = 393,216 w
  short* Wb2 = (short*)(fp + 393216);
  float* pooled = fp + 2 * 393216;                  // 3072*512  = 1,572,864
  float* ze     = pooled + 1572864;                 // 3072*256  =   786,432
  float* dotb   = ze + 786432;                      // 3072*1024 = 3,145,728
  float* cbsq   = dotb + 3145728;                   //     1,024
  float* zall   = cbsq + 1024;                      //   786,432
  float* cpart  = zall + 786432;                    //     3,072
  float* h1     = cpart + 3072;                     //    65,536
  float* h2     = h1 + 65536;                       //    65,536
  float* S      = h2 + 65536;                       //   786,432
  float* h2c    = S + 786432;                       //   196,608
  float* d2wT   = h2c + 196608;                     // 2,097,152
  float* logitsb= d2wT + 2097152;                   // 1,572,864
  float* lseb   = logitsb + 1572864;                //     1,536
  float* rpart  = lseb + 1536;                      //       256
  // total ~32.3M words ~129 MB

  const short* X = XbS + 512;   // row 0 = first real row; row -1 = guard
  short* Yv = YbS + 512;

  // ---- prep (independent of tokens) ----
  k_guard    <<<8, 256, 0, stream>>>(XbS, YbS);
  k_wconv    <<<6144, 256, 0, stream>>>(c1w, c2w, Wb1, Wb2);
  k_buildS   <<<3072, 256, 0, stream>>>(d1w, S);
  k_transpose<<<dim3(128, 16), 256, 0, stream>>>(d2w, d2wT);
  k_cbsq     <<<1024, 256, 0, stream>>>(cbk, cbsq);

  // ---- encoder, all 3 segments batched ----
  k_embed     <<<79872, 256, 0, stream>>>(tok_prev, tok_curr, tok_next, emb, XbS);
  k_conv3_mfma<<<dim3(312, 4), 256, 0, stream>>>(X, Wb1, c1b, Yv);
  k_conv3_mfma<<<dim3(312, 4), 256, 0, stream>>>((const short*)Yv, Wb2, c2b, (short*)X);
  k_pool      <<<768, 256, 0, stream>>>(X, pooled);
  k_gemm_abt  <<<dim3(48, 4),  256, 0, stream>>>(pooled, c3w, ze, 512, 256, c3b, 0);
  k_gemm_abt  <<<dim3(48, 16), 256, 0, stream>>>(ze, cbk, dotb, 256, 1024, nullptr, 0);
  k_vq        <<<3072, 256, 0, stream>>>(dotb, cbsq, ze, cbk, zall, cpart);

  // ---- decoder ----
  k_gemm_abt<<<dim3(2, 8), 256, 0, stream>>>(zall, fc1w, h1, 6144, 512, fc1b, 1);
  k_gemm_abt<<<dim3(2, 8), 256, 0, stream>>>(h1, fc2w, h2, 512, 512, fc2b, 1);
  for (int cls = 0; cls < 3; ++cls)
    k_gemm_abt<<<dim3(2, 8), 256, 0, stream>>>(h2, S + cls * 262144, h2c + cls * 65536,
                                               512, 512, d1b, 1);
  k_gemm_abt<<<dim3(6, 64), 256, 0, stream>>>(h2c, d2wT, logitsb, 512, 4096, d2b, 0);

  k_lse  <<<1536, 256, 0, stream>>>(logitsb, lseb);
  k_recon<<<200, 256, 0, stream>>>(tok_curr, logitsb, lseb, rpart);
  k_final<<<1, 256, 0, stream>>>(rpart, cpart, (float*)d_out);
}

// Round 3
// 483.407 us; speedup vs baseline: 8.5187x; 4.2429x over previous
//
#include <hip/hip_runtime.h>
#include <math.h>

#define B_    128
#define T_    100
#define TPAD  104
#define CB_   4
#define EMB_  128
#define HIDC  512
#define LAT_  256
#define NC_   1024
#define NROW  39936          // 3*128*104 padded rows (all 3 segments)

typedef __attribute__((ext_vector_type(8))) short short8;
typedef __attribute__((ext_vector_type(4))) float f32x4;

__device__ __forceinline__ short f2bf(float x) {
  unsigned u = __builtin_bit_cast(unsigned, x);
  u += 0x7fffu + ((u >> 16) & 1u);
  return (short)(u >> 16);
}
__device__ __forceinline__ float bf2f(short s) {
  unsigned u = ((unsigned)(unsigned short)s) << 16;
  return __builtin_bit_cast(float, u);
}

// ---------------- zero guard rows (raw row 0 and NROW+1) of both bf16 buffers ----------------
__global__ void k_guard(short* __restrict__ a, short* __restrict__ b) {
  int id = blockIdx.x * 256 + threadIdx.x;      // 2048
  short* buf = (id >> 10) ? b : a;
  int rem = id & 1023;
  int row = rem >> 9, c = rem & 511;
  long off = row ? ((long)(NROW + 1) * 512 + c) : c;
  buf[off] = 0;
}

// ---------------- convert both conv weights to bf16 layout [tap][o][i] ----------------
__global__ void k_wconv(const float* __restrict__ w1, const float* __restrict__ w2,
                        short* __restrict__ o1, short* __restrict__ o2) {
  int id = blockIdx.x * 256 + threadIdx.x;      // 2*786432 exact
  const float* w = (id < 786432) ? w1 : w2;
  short* o = (id < 786432) ? o1 : o2;
  int local = id & 786431;
  int i = local & 511;
  int oo = (local >> 9) & 511;
  int tap = local >> 18;
  o[local] = f2bf(w[oo * 1536 + i * 3 + tap]);
}

// ---------------- embedding gather (all 3 segs) -> bf16 padded buffer ----------------
__global__ void k_embed(const int* __restrict__ t0, const int* __restrict__ t1,
                        const int* __restrict__ t2, const float* __restrict__ emb,
                        short* __restrict__ x) {   // x = raw base (guard at row 0)
  int id = blockIdx.x * 256 + threadIdx.x;      // NROW*512 = 20,447,232 exact
  int c = id & 511;
  int row = id >> 9;
  int t = row % TPAD;
  int sb = row / TPAD;
  int b = sb & 127, s = sb >> 7;
  short v = 0;
  if (t < T_) {
    const int* tok = (s == 0) ? t0 : (s == 1) ? t1 : t2;
    int tk = tok[(b * T_ + t) * CB_ + (c >> 7)];
    v = f2bf(emb[tk * EMB_ + (c & 127)]);
  }
  x[(long)(row + 1) * 512 + c] = v;
}

// ---------------- 3-tap conv via bf16 MFMA 16x16x32 ----------------
#define MFMA16(a, b, c) __builtin_amdgcn_mfma_f32_16x16x32_bf16(a, b, c, 0, 0, 0)
#define SWZ(row, slot) (((slot) + ((row) >> 1)) & 3)

__global__ __launch_bounds__(256) void k_conv3_mfma(const short* __restrict__ X,
                                                    const short* __restrict__ Wb,
                                                    const float* __restrict__ bias,
                                                    short* __restrict__ Y) {
  __shared__ short8 sA[130][4];
  __shared__ short8 sB[3][128][4];
  int r0 = blockIdx.x * 128;
  int o0 = blockIdx.y * 128;
  int tid = threadIdx.x;
  int lane = tid & 63, wid = tid >> 6;
  int wm = wid >> 1, wn = wid & 1;
  int ls = lane >> 4, lr = lane & 15;
  f32x4 acc[4][4] = {};
  for (int kc = 0; kc < 512; kc += 32) {
    __syncthreads();
    #pragma unroll
    for (int j = 0; j < 3; ++j) {
      int idx = tid + 256 * j;
      if (idx < 520) {
        int row = idx >> 2, slot = idx & 3;
        const short8* gp = (const short8*)(X + (long)(r0 - 1 + row) * 512 + kc);
        sA[row][SWZ(row, slot)] = gp[slot];
      }
    }
    #pragma unroll
    for (int j = 0; j < 6; ++j) {
      int idx = tid + 256 * j;
      int tap = idx >> 9, rem = idx & 511;
      int row = rem >> 2, slot = rem & 3;
      const short8* gp = (const short8*)(Wb + ((tap * 512) + o0 + row) * 512 + kc);
      sB[tap][row][SWZ(row, slot)] = gp[slot];
    }
    __syncthreads();
    #pragma unroll
    for (int tap = 0; tap < 3; ++tap) {
      short8 a[4], b[4];
      #pragma unroll
      for (int m = 0; m < 4; ++m) {
        int row = wm * 64 + m * 16 + lr + tap;
        a[m] = sA[row][SWZ(row, ls)];
      }
      #pragma unroll
      for (int n = 0; n < 4; ++n) {
        int row = wn * 64 + n * 16 + lr;
        b[n] = sB[tap][row][SWZ(row, ls)];
      }
      #pragma unroll
      for (int m = 0; m < 4; ++m)
        #pragma unroll
        for (int n = 0; n < 4; ++n)
          acc[m][n] = MFMA16(a[m], b[n], acc[m][n]);
    }
  }
  #pragma unroll
  for (int m = 0; m < 4; ++m) {
    #pragma unroll
    for (int n = 0; n < 4; ++n) {
      int col = o0 + wn * 64 + n * 16 + lr;
      float bv = bias[col];
      #pragma unroll
      for (int j = 0; j < 4; ++j) {
        int r = r0 + wm * 64 + m * 16 + ls * 4 + j;
        int t = r % TPAD;
        float v = (t < T_) ? fmaxf(acc[m][n][j] + bv, 0.f) : 0.f;
        Y[(long)r * 512 + col] = f2bf(v);
      }
    }
  }
}

// ---------------- adaptive pool: 13 taps, 1/13 each; bf16 in, f32 out ----------------
__global__ void k_pool(const short* __restrict__ Xg, float* __restrict__ pooled) {
  int id = blockIdx.x * 256 + threadIdx.x;   // 3072*64 = 196608 exact
  int row = id >> 6, cg = id & 63;
  int s = row >> 10, bp = row & 1023;
  int b = bp >> 3, p = bp & 7;
  int t0 = (p * 25) >> 1;
  const short8* src = (const short8*)(Xg + (long)((s * 128 + b) * TPAD + t0) * 512) + cg;
  float acc[8] = {};
  #pragma unroll
  for (int j = 0; j < 13; ++j) {
    short8 v = src[j * 64];
    #pragma unroll
    for (int k = 0; k < 8; ++k) acc[k] += bf2f(v[k]);
  }
  float4 lo, hi;
  lo.x = acc[0] * (1.f / 13.f); lo.y = acc[1] * (1.f / 13.f);
  lo.z = acc[2] * (1.f / 13.f); lo.w = acc[3] * (1.f / 13.f);
  hi.x = acc[4] * (1.f / 13.f); hi.y = acc[5] * (1.f / 13.f);
  hi.z = acc[6] * (1.f / 13.f); hi.w = acc[7] * (1.f / 13.f);
  *(float4*)&pooled[(long)row * 512 + cg * 8] = lo;
  *(float4*)&pooled[(long)row * 512 + cg * 8 + 4] = hi;
}

// ---------------- FMA helper ----------------
__device__ __forceinline__ void fma4x4(const float4& a, const float4& b, float acc[4][4]) {
  acc[0][0] = fmaf(a.x, b.x, acc[0][0]);
  acc[0][1] = fmaf(a.x, b.y, acc[0][1]);
  acc[0][2] = fmaf(a.x, b.z, acc[0][2]);
  acc[0][3] = fmaf(a.x, b.w, acc[0][3]);
  acc[1][0] = fmaf(a.y, b.x, acc[1][0]);
  acc[1][1] = fmaf(a.y, b.y, acc[1][1]);
  acc[1][2] = fmaf(a.y, b.z, acc[1][2]);
  acc[1][3] = fmaf(a.y, b.w, acc[1][3]);
  acc[2][0] = fmaf(a.z, b.x, acc[2][0]);
  acc[2][1] = fmaf(a.z, b.y, acc[2][1]);
  acc[2][2] = fmaf(a.z, b.z, acc[2][2]);
  acc[2][3] = fmaf(a.z, b.w, acc[2][3]);
  acc[3][0] = fmaf(a.w, b.x, acc[3][0]);
  acc[3][1] = fmaf(a.w, b.y, acc[3][1]);
  acc[3][2] = fmaf(a.w, b.z, acc[3][2]);
  acc[3][3] = fmaf(a.w, b.w, acc[3][3]);
}

// ---------------- generic fp32 tiled GEMM: C = act(A[M][K] @ B[N][K]^T + bias) ----------------
__global__ __launch_bounds__(256) void k_gemm_abt(const float* __restrict__ A,
                                                  const float* __restrict__ Bm,
                                                  float* __restrict__ C,
                                                  int K, int N,
                                                  const float* __restrict__ bias,
                                                  int relu) {
  __shared__ float As[32][68];
  __shared__ float Bs[32][68];
  int r0 = blockIdx.x * 64, c0 = blockIdx.y * 64;
  int tid = threadIdx.x, tc = tid & 15, tr = tid >> 4;
  float acc[4][4] = {};
  for (int kc = 0; kc < K; kc += 32) {
    __syncthreads();
    #pragma unroll
    for (int j = 0; j < 8; ++j) {
      int idx = tid + 256 * j;
      int row = idx >> 5, kk = idx & 31;
      As[kk][row] = A[(r0 + row) * K + kc + kk];
      Bs[kk][row] = Bm[(c0 + row) * K + kc + kk];
    }
    __syncthreads();
    #pragma unroll 8
    for (int kk = 0; kk < 32; ++kk) {
      float4 a = *(const float4*)&As[kk][tr * 4];
      float4 b = *(const float4*)&Bs[kk][tc * 4];
      fma4x4(a, b, acc);
    }
  }
  #pragma unroll
  for (int rr = 0; rr < 4; ++rr) {
    int r = r0 + tr * 4 + rr;
    int c = c0 + tc * 4;
    float4 v;
    v.x = acc[rr][0]; v.y = acc[rr][1]; v.z = acc[rr][2]; v.w = acc[rr][3];
    if (bias) { v.x += bias[c]; v.y += bias[c + 1]; v.z += bias[c + 2]; v.w += bias[c + 3]; }
    if (relu) { v.x = fmaxf(v.x, 0.f); v.y = fmaxf(v.y, 0.f); v.z = fmaxf(v.z, 0.f); v.w = fmaxf(v.w, 0.f); }
    *(float4*)&C[r * N + c] = v;
  }
}

// ---------------- split-K GEMM stage 1: part[z][M][N] partial sums ----------------
// grid (M/64, N/64, G*KS); group g = z/KS uses B + g*bgstride; chunk zz = z%KS.
__global__ __launch_bounds__(256) void k_gemm_splitk(const float* __restrict__ A,
                                                     const float* __restrict__ B,
                                                     float* __restrict__ part,
                                                     int M, int N, int K,
                                                     int kchunk, int KS, long bgstride) {
  __shared__ float As[32][68];
  __shared__ float Bs[32][68];
  int r0 = blockIdx.x * 64, c0 = blockIdx.y * 64;
  int bz = blockIdx.z;
  int g = bz / KS, zz = bz - g * KS;
  const float* Bg = B + (long)g * bgstride;
  int k0 = zz * kchunk;
  int tid = threadIdx.x, tc = tid & 15, tr = tid >> 4;
  float acc[4][4] = {};
  for (int kc = k0; kc < k0 + kchunk; kc += 32) {
    __syncthreads();
    #pragma unroll
    for (int j = 0; j < 8; ++j) {
      int idx = tid + 256 * j;
      int row = idx >> 5, kk = idx & 31;
      As[kk][row] = A[(long)(r0 + row) * K + kc + kk];
      Bs[kk][row] = Bg[(long)(c0 + row) * K + kc + kk];
    }
    __syncthreads();
    #pragma unroll 8
    for (int kk = 0; kk < 32; ++kk) {
      float4 a = *(const float4*)&As[kk][tr * 4];
      float4 b = *(const float4*)&Bs[kk][tc * 4];
      fma4x4(a, b, acc);
    }
  }
  float* P = part + (long)bz * M * N;
  #pragma unroll
  for (int rr = 0; rr < 4; ++rr) {
    int r = r0 + tr * 4 + rr;
    int c = c0 + tc * 4;
    float4 v;
    v.x = acc[rr][0]; v.y = acc[rr][1]; v.z = acc[rr][2]; v.w = acc[rr][3];
    *(float4*)&P[(long)r * N + c] = v;
  }
}

// ---------------- split-K stage 2: C[g][m][n] = act(bias + sum_j part[g*KS+j][m][n]) ----------------
__global__ void k_reduce_act(const float* __restrict__ part, float* __restrict__ C,
                             const float* __restrict__ bias, int N, int MN,
                             int KS, int relu, int total4) {
  int id = blockIdx.x * 256 + threadIdx.x;
  if (id >= total4) return;
  int e = id * 4;
  int g = e / MN;
  int rem = e - g * MN;
  const float* base = part + (long)g * KS * MN + rem;
  float4 s = *(const float4*)base;
  for (int j = 1; j < KS; ++j) {
    float4 v = *(const float4*)(base + (long)j * MN);
    s.x += v.x; s.y += v.y; s.z += v.z; s.w += v.w;
  }
  int c = rem % N;
  s.x += bias[c]; s.y += bias[c + 1]; s.z += bias[c + 2]; s.w += bias[c + 3];
  if (relu) {
    s.x = fmaxf(s.x, 0.f); s.y = fmaxf(s.y, 0.f);
    s.z = fmaxf(s.z, 0.f); s.w = fmaxf(s.w, 0.f);
  }
  *(float4*)&C[(long)g * MN + rem] = s;
}

// ---------------- codebook squared norms ----------------
__global__ void k_cbsq(const float* __restrict__ cb, float* __restrict__ cbsq) {
  __shared__ float sm[256];
  int k = blockIdx.x, tid = threadIdx.x;
  float v = cb[k * 256 + tid];
  sm[tid] = v * v;
  __syncthreads();
  for (int off = 128; off; off >>= 1) { if (tid < off) sm[tid] += sm[tid + off]; __syncthreads(); }
  if (tid == 0) cbsq[k] = sm[0];
}

// ---------------- VQ argmin + gather + commit partial (all 3 segs) ----------------
__global__ __launch_bounds__(256) void k_vq(const float* __restrict__ dot,
                                            const float* __restrict__ cbsq,
                                            const float* __restrict__ ze,
                                            const float* __restrict__ cb,
                                            float* __restrict__ zall,
                                            float* __restrict__ commit_part) {
  __shared__ float sv[256];
  __shared__ int si[256];
  int row = blockIdx.x, tid = threadIdx.x;   // row = s*1024 + b*8 + p
  float best = 3.4e38f; int bi = 0;
  #pragma unroll
  for (int j = 0; j < 4; ++j) {
    int k = tid * 4 + j;
    float d = cbsq[k] - 2.f * dot[(long)row * 1024 + k];
    if (d < best) { best = d; bi = k; }
  }
  sv[tid] = best; si[tid] = bi;
  __syncthreads();
  for (int off = 128; off; off >>= 1) {
    if (tid < off) {
      float o = sv[tid + off]; int oi = si[tid + off];
      if (o < sv[tid] || (o == sv[tid] && oi < si[tid])) { sv[tid] = o; si[tid] = oi; }
    }
    __syncthreads();
  }
  int ks = si[0];
  float zq = cb[ks * 256 + tid];
  float zev = ze[(long)row * 256 + tid];
  int s = row >> 10, bp = row & 1023;
  int b = bp >> 3, p = bp & 7;
  zall[b * 6144 + s * 2048 + p * 256 + tid] = zq;
  float d = zev - zq;
  __syncthreads();
  sv[tid] = d * d;
  __syncthreads();
  for (int off = 128; off; off >>= 1) { if (tid < off) sv[tid] += sv[tid + off]; __syncthreads(); }
  if (tid == 0) commit_part[row] = sv[0];
}

// ---------------- deconv1 collapsed tap-sum weights: S[cls][o][i] ----------------
__global__ void k_buildS(const float* __restrict__ d1w, float* __restrict__ S) {
  int id = blockIdx.x * 256 + threadIdx.x;   // 3*512*512 exact
  int i = id & 511;
  int o = (id >> 9) & 511;
  int cls = id >> 18;
  const float* w = d1w + (i * 512 + o) * 3;
  float v;
  if (cls == 0)      v = w[0] + w[1];
  else if (cls == 1) v = w[0] + w[1] + w[2];
  else               v = w[1] + w[2];
  S[(cls * 512 + o) * 512 + i] = v;
}

// ---------------- transpose d2w [512][4096] -> [4096][512] ----------------
__global__ void k_transpose(const float* __restrict__ src, float* __restrict__ dst) {
  __shared__ float tile[32][33];
  int bx = blockIdx.x, by = blockIdx.y;
  int tx = threadIdx.x & 31, ty = threadIdx.x >> 5;
  #pragma unroll
  for (int j = 0; j < 32; j += 8)
    tile[ty + j][tx] = src[(by * 32 + ty + j) * 4096 + bx * 32 + tx];
  __syncthreads();
  #pragma unroll
  for (int j = 0; j < 32; j += 8)
    dst[(bx * 32 + ty + j) * 512 + by * 32 + tx] = tile[tx][ty + j];
}

// ---------------- logsumexp over each 1024-vocab row ----------------
__global__ __launch_bounds__(256) void k_lse(const float* __restrict__ logits,
                                             float* __restrict__ lse) {
  __shared__ float sm[256];
  int blk = blockIdx.x;                       // cls*512 + b*4 + cb
  int cb_i = blk & 3, b = (blk >> 2) & 127, cls = blk >> 9;
  const float* rp = logits + (cls * 128 + b) * 4096 + cb_i * 1024;
  int tid = threadIdx.x;
  float v0 = rp[tid], v1 = rp[tid + 256], v2 = rp[tid + 512], v3 = rp[tid + 768];
  float m = fmaxf(fmaxf(v0, v1), fmaxf(v2, v3));
  sm[tid] = m; __syncthreads();
  for (int off = 128; off; off >>= 1) { if (tid < off) sm[tid] = fmaxf(sm[tid], sm[tid + off]); __syncthreads(); }
  float gm = sm[0]; __syncthreads();
  float e = expf(v0 - gm) + expf(v1 - gm) + expf(v2 - gm) + expf(v3 - gm);
  sm[tid] = e; __syncthreads();
  for (int off = 128; off; off >>= 1) { if (tid < off) sm[tid] += sm[tid + off]; __syncthreads(); }
  if (tid == 0) lse[blk] = gm + logf(sm[0]);
}

// ---------------- recon nll partial sums ----------------
__global__ void k_recon(const int* __restrict__ tok, const float* __restrict__ logits,
                        const float* __restrict__ lse, float* __restrict__ part) {
  __shared__ float sm[256];
  int id = blockIdx.x * 256 + threadIdx.x;    // 51200 exact
  int cb_i = id & 3;
  int t = (id >> 2) % 100;
  int b = id / 400;
  int tk = tok[id];
  int cls = (t == 0) ? 0 : ((t == 99) ? 2 : 1);
  float val = lse[cls * 512 + b * 4 + cb_i]
            - logits[(cls * 128 + b) * 4096 + cb_i * 1024 + tk];
  int tid = threadIdx.x;
  sm[tid] = val; __syncthreads();
  for (int off = 128; off; off >>= 1) { if (tid < off) sm[tid] += sm[tid + off]; __syncthreads(); }
  if (tid == 0) part[blockIdx.x] = sm[0];
}

// ---------------- final: total = recon_mean + 0.1 * commit_mean_sum ----------------
__global__ void k_final(const float* __restrict__ rpart, const float* __restrict__ cpart,
                        float* __restrict__ out) {
  __shared__ float sm[256];
  __shared__ float rs;
  int tid = threadIdx.x;
  float r = (tid < 200) ? rpart[tid] : 0.f;
  sm[tid] = r; __syncthreads();
  for (int off = 128; off; off >>= 1) { if (tid < off) sm[tid] += sm[tid + off]; __syncthreads(); }
  if (tid == 0) rs = sm[0];
  __syncthreads();
  float c = 0.f;
  #pragma unroll
  for (int j = 0; j < 12; ++j) c += cpart[tid + 256 * j];
  sm[tid] = c; __syncthreads();
  for (int off = 128; off; off >>= 1) { if (tid < off) sm[tid] += sm[tid + off]; __syncthreads(); }
  if (tid == 0) out[0] = rs / 51200.f + 0.1f * (sm[0] / 262144.f);
}

extern "C" void kernel_launch(void* const* d_in, const int* in_sizes, int n_in,
                              void* d_out, int out_size, void* d_ws, size_t ws_size,
                              hipStream_t stream) {
  const int*   tok_prev = (const int*)d_in[0];
  const int*   tok_curr = (const int*)d_in[1];
  const int*   tok_next = (const int*)d_in[2];
  const float* emb  = (const float*)d_in[3];
  const float* c1w  = (const float*)d_in[4];
  const float* c1b  = (const float*)d_in[5];
  const float* c2w  = (const float*)d_in[6];
  const float* c2b  = (const float*)d_in[7];
  const float* c3w  = (const float*)d_in[8];
  const float* c3b  = (const float*)d_in[9];
  const float* cbk  = (const float*)d_in[10];
  const float* fc1w = (const float*)d_in[11];
  const float* fc1b = (const float*)d_in[12];
  const float* fc2w = (const float*)d_in[13];
  const float* fc2b = (const float*)d_in[14];
  const float* d1w  = (const float*)d_in[15];
  const float* d1b  = (const float*)d_in[16];
  const float* d2w  = (const float*)d_in[17];
  const float* d2b  = (const float*)d_in[18];

  // ---- workspace layout (f32 word offsets) ----
  float* ws = (float*)d_ws;
  short* XbS = (short*)ws;                          // bf16, guard at row0
  short* YbS = (short*)(ws + 10224128);
  float* fp  = ws + 2 * 10224128;
  short* Wb1 = (short*)fp;                          //  393,216 w
  short* Wb2 = (short*)(fp + 393216);
  float* pooled = fp + 2 * 393216;                  // 1,572,864
  float* ze     = pooled + 1572864;                 //   786,432
  float* dotb   = ze + 786432;                      // 3,145,728 (reused as split-K partials)
  float* cbsq   = dotb + 3145728;
  float* zall   = cbsq + 1024;                      //   786,432
  float* cpart  = zall + 786432;                    //     3,072
  float* h1     = cpart + 3072;                     //    65,536
  float* h2     = h1 + 65536;                       //    65,536
  float* S      = h2 + 65536;                       //   786,432
  float* h2c    = S + 786432;                       //   196,608
  float* d2wT   = h2c + 196608;                     // 2,097,152
  float* logitsb= d2wT + 2097152;                   // 1,572,864
  float* lseb   = logitsb + 1572864;
  float* rpart  = lseb + 1536;

  const short* X = XbS + 512;
  short* Yv = YbS + 512;
  float* part = dotb;   // dot values are consumed by k_vq before the decoder runs

  // ---- prep (independent of tokens) ----
  k_guard    <<<8, 256, 0, stream>>>(XbS, YbS);
  k_wconv    <<<6144, 256, 0, stream>>>(c1w, c2w, Wb1, Wb2);
  k_buildS   <<<3072, 256, 0, stream>>>(d1w, S);
  k_transpose<<<dim3(128, 16), 256, 0, stream>>>(d2w, d2wT);
  k_cbsq     <<<1024, 256, 0, stream>>>(cbk, cbsq);

  // ---- encoder, all 3 segments batched ----
  k_embed     <<<79872, 256, 0, stream>>>(tok_prev, tok_curr, tok_next, emb, XbS);
  k_conv3_mfma<<<dim3(312, 4), 256, 0, stream>>>(X, Wb1, c1b, Yv);
  k_conv3_mfma<<<dim3(312, 4), 256, 0, stream>>>((const short*)Yv, Wb2, c2b, (short*)X);
  k_pool      <<<768, 256, 0, stream>>>(X, pooled);
  k_gemm_abt  <<<dim3(48, 4),  256, 0, stream>>>(pooled, c3w, ze, 512, 256, c3b, 0);
  k_gemm_abt  <<<dim3(48, 16), 256, 0, stream>>>(ze, cbk, dotb, 256, 1024, nullptr, 0);
  k_vq        <<<3072, 256, 0, stream>>>(dotb, cbsq, ze, cbk, zall, cpart);

  // ---- decoder (split-K two-stage for parallelism) ----
  // fc1: M=128 N=512 K=6144, 16 chunks of 384
  k_gemm_splitk<<<dim3(2, 8, 16), 256, 0, stream>>>(zall, fc1w, part, 128, 512, 6144, 384, 16, 0);
  k_reduce_act <<<64, 256, 0, stream>>>(part, h1, fc1b, 512, 65536, 16, 1, 16384);
  // fc2: K=512, 4 chunks of 128
  k_gemm_splitk<<<dim3(2, 8, 4), 256, 0, stream>>>(h1, fc2w, part, 128, 512, 512, 128, 4, 0);
  k_reduce_act <<<64, 256, 0, stream>>>(part, h2, fc2b, 512, 65536, 4, 1, 16384);
  // deconv1 collapsed: 3 groups (cls) x 4 chunks of 128
  k_gemm_splitk<<<dim3(2, 8, 12), 256, 0, stream>>>(h2, S, part, 128, 512, 512, 128, 4, 262144);
  k_reduce_act <<<192, 256, 0, stream>>>(part, h2c, d1b, 512, 65536, 4, 1, 49152);
  // logits: M=384 N=4096 K=512, 2 chunks of 256
  k_gemm_splitk<<<dim3(6, 64, 2), 256, 0, stream>>>(h2c, d2wT, part, 384, 4096, 512, 256, 2, 0);
  k_reduce_act <<<1536, 256, 0, stream>>>(part, logitsb, d2b, 4096, 1572864, 2, 0, 393216);

  k_lse  <<<1536, 256, 0, stream>>>(logitsb, lseb);
  k_recon<<<200, 256, 0, stream>>>(tok_curr, logitsb, lseb, rpart);
  k_final<<<1, 256, 0, stream>>>(rpart, cpart, (float*)d_out);
}

// Round 4
// 345.312 us; speedup vs baseline: 11.9254x; 1.3999x over previous
//
#include <hip/hip_runtime.h>
#include <math.h>

#define B_    128
#define T_    100
#define TPAD  104
#define CB_   4
#define EMB_  128
#define HIDC  512
#define LAT_  256
#define NC_   1024
#define NROW  39936          // 3*128*104 padded rows (all 3 segments)

typedef __attribute__((ext_vector_type(8))) short short8;
typedef __attribute__((ext_vector_type(4))) float f32x4;

__device__ __forceinline__ short f2bf(float x) {
  unsigned u = __builtin_bit_cast(unsigned, x);
  u += 0x7fffu + ((u >> 16) & 1u);
  return (short)(u >> 16);
}
__device__ __forceinline__ float bf2f(short s) {
  unsigned u = ((unsigned)(unsigned short)s) << 16;
  return __builtin_bit_cast(float, u);
}

#define GLOAD_LDS(g, l) __builtin_amdgcn_global_load_lds( \
    (const __attribute__((address_space(1))) void*)(g),   \
    (__attribute__((address_space(3))) void*)(l), 16, 0, 0)

#define MFMA16(a, b, c) __builtin_amdgcn_mfma_f32_16x16x32_bf16(a, b, c, 0, 0, 0)
#define SWZ(row, slot) (((slot) + ((row) >> 1)) & 3)

// ---------------- zero guard rows (raw row 0 and NROW+1) of both bf16 buffers ----------------
__global__ void k_guard(short* __restrict__ a, short* __restrict__ b) {
  int id = blockIdx.x * 256 + threadIdx.x;      // 2048
  short* buf = (id >> 10) ? b : a;
  int rem = id & 1023;
  int row = rem >> 9, c = rem & 511;
  long off = row ? ((long)(NROW + 1) * 512 + c) : c;
  buf[off] = 0;
}

// ---------------- convert weights to bf16: conv1/conv2 -> [tap][o][i]; c3w, cbk -> row-major copy ----------------
__global__ void k_cvt(const float* __restrict__ c1w, const float* __restrict__ c2w,
                      const float* __restrict__ c3w, const float* __restrict__ cbk,
                      short* __restrict__ Wb1, short* __restrict__ Wb2,
                      short* __restrict__ c3wB, short* __restrict__ cbkB) {
  int id = blockIdx.x * 256 + threadIdx.x;      // 1,966,080 exact
  if (id < 1572864) {
    const float* w = (id < 786432) ? c1w : c2w;
    short* o = (id < 786432) ? Wb1 : Wb2;
    int local = id & 786431;
    int i = local & 511;
    int oo = (local >> 9) & 511;
    int tap = local >> 18;
    o[local] = f2bf(w[oo * 1536 + i * 3 + tap]);
  } else if (id < 1703936) {
    int local = id - 1572864;
    c3wB[local] = f2bf(c3w[local]);
  } else {
    int local = id - 1703936;
    cbkB[local] = f2bf(cbk[local]);
  }
}

// ---------------- embedding gather (all 3 segs) -> bf16 padded buffer, short8 per thread ----------------
__global__ void k_embed(const int* __restrict__ t0, const int* __restrict__ t1,
                        const int* __restrict__ t2, const float* __restrict__ emb,
                        short* __restrict__ x) {   // x = raw base (guard at row 0)
  int id = blockIdx.x * 256 + threadIdx.x;      // NROW*64 = 2,555,904 exact
  int c8 = id & 63;
  int row = id >> 6;
  int t = row % TPAD;
  int sb = row / TPAD;
  int b = sb & 127, s = sb >> 7;
  short8 v = {};
  if (t < T_) {
    const int* tok = (s == 0) ? t0 : (s == 1) ? t1 : t2;
    int tk = tok[(b * T_ + t) * CB_ + (c8 >> 4)];
    const float* e = emb + tk * EMB_ + (c8 & 15) * 8;
    float4 f0 = *(const float4*)e;
    float4 f1 = *(const float4*)(e + 4);
    v[0] = f2bf(f0.x); v[1] = f2bf(f0.y); v[2] = f2bf(f0.z); v[3] = f2bf(f0.w);
    v[4] = f2bf(f1.x); v[5] = f2bf(f1.y); v[6] = f2bf(f1.z); v[7] = f2bf(f1.w);
  }
  ((short8*)x)[(long)(row + 1) * 64 + c8] = v;
}

// ---------------- 3-tap conv via bf16 MFMA, global_load_lds staging ----------------
// X: bf16 rows, valid [-1 .. NROW]; Wb: [3][512(o)][512(i)]; Y: rows [0..NROW)
__global__ __launch_bounds__(256) void k_conv3_mfma(const short* __restrict__ X,
                                                    const short* __restrict__ Wb,
                                                    const float* __restrict__ bias,
                                                    short* __restrict__ Y) {
  __shared__ short sm[16896];     // A: 144 rows x 32 (4608) + B: 3*128 rows x 32 (12288)
  int r0 = blockIdx.x * 128;
  int o0 = blockIdx.y * 128;
  int tid = threadIdx.x;
  int lane = tid & 63, wid = tid >> 6;
  int wm = wid >> 1, wn = wid & 1;
  int ls = lane >> 4, lr = lane & 15;
  // per-lane source slot permutation (chunk-invariant): lane l stages LDS slot l&3,
  // which must hold global slot g = ((l&3) - (row>>1)) & 3, row = 16q + (l>>2).
  int g = ((lane & 3) - ((lane >> 3) & 3)) & 3;
  long laneoff = (long)(lane >> 2) * 512 + g * 8;

  const short* gp[9];
  const short* lp[9];
  #pragma unroll
  for (int i = 0; i < 9; ++i) {
    int q = wid + 4 * i;
    if (q < 33) {
      long base;
      const short* src;
      if (q < 9) { src = X; base = (long)(r0 - 1 + 16 * q) * 512; }
      else {
        int b = q - 9, tap = b >> 3, j = b & 7;
        src = Wb; base = (long)(tap * 512 + o0 + 16 * j) * 512;
      }
      gp[i] = src + base + laneoff;
      lp[i] = sm + q * 512;
    }
  }

  f32x4 acc[4][4] = {};
  for (int kc = 0; kc < 512; kc += 32) {
    __syncthreads();
    #pragma unroll
    for (int i = 0; i < 9; ++i) {
      int q = wid + 4 * i;
      if (q < 33) {
        GLOAD_LDS(gp[i], lp[i]);
        gp[i] += 32;
      }
    }
    __syncthreads();
    const short8* A8 = (const short8*)sm;
    const short8* B8 = (const short8*)(sm + 4608);
    #pragma unroll
    for (int tap = 0; tap < 3; ++tap) {
      short8 a[4], b[4];
      #pragma unroll
      for (int m = 0; m < 4; ++m) {
        int row = wm * 64 + m * 16 + lr + tap;
        a[m] = A8[row * 4 + SWZ(row, ls)];
      }
      #pragma unroll
      for (int n = 0; n < 4; ++n) {
        int row = wn * 64 + n * 16 + lr;
        b[n] = B8[(tap * 128 + row) * 4 + SWZ(row, ls)];
      }
      #pragma unroll
      for (int m = 0; m < 4; ++m)
        #pragma unroll
        for (int n = 0; n < 4; ++n)
          acc[m][n] = MFMA16(a[m], b[n], acc[m][n]);
    }
  }
  #pragma unroll
  for (int m = 0; m < 4; ++m) {
    #pragma unroll
    for (int n = 0; n < 4; ++n) {
      int col = o0 + wn * 64 + n * 16 + lr;
      float bv = bias[col];
      #pragma unroll
      for (int j = 0; j < 4; ++j) {
        int r = r0 + wm * 64 + m * 16 + ls * 4 + j;
        int t = r % TPAD;
        float v = (t < T_) ? fmaxf(acc[m][n][j] + bv, 0.f) : 0.f;
        Y[(long)r * 512 + col] = f2bf(v);
      }
    }
  }
}

// ---------------- bf16 MFMA GEMM: C[M][N] = act(A[M][K] @ B[N][K]^T + bias), 128x128 tile ----------------
__global__ __launch_bounds__(256) void k_gemm_mfma(const short* __restrict__ A,
                                                   const short* __restrict__ B,
                                                   float* __restrict__ C,
                                                   short* __restrict__ Cb,
                                                   const float* __restrict__ bias,
                                                   int K, int N, int relu) {
  __shared__ short sm[8192];      // A: 128x32 (4096) + B: 128x32 (4096)
  int r0 = blockIdx.x * 128;
  int o0 = blockIdx.y * 128;
  int tid = threadIdx.x;
  int lane = tid & 63, wid = tid >> 6;
  int wm = wid >> 1, wn = wid & 1;
  int ls = lane >> 4, lr = lane & 15;
  int g = ((lane & 3) - ((lane >> 3) & 3)) & 3;
  long laneoff = (long)(lane >> 2) * K + g * 8;

  const short* gp[4];
  const short* lp[4];
  #pragma unroll
  for (int i = 0; i < 4; ++i) {
    int q = wid + 4 * i;   // 0..15
    const short* src;
    long base;
    if (q < 8) { src = A; base = (long)(r0 + 16 * q) * K; }
    else       { src = B; base = (long)(o0 + 16 * (q - 8)) * K; }
    gp[i] = src + base + laneoff;
    lp[i] = sm + q * 512;
  }

  f32x4 acc[4][4] = {};
  for (int kc = 0; kc < K; kc += 32) {
    __syncthreads();
    #pragma unroll
    for (int i = 0; i < 4; ++i) {
      GLOAD_LDS(gp[i], lp[i]);
      gp[i] += 32;
    }
    __syncthreads();
    const short8* A8 = (const short8*)sm;
    const short8* B8 = (const short8*)(sm + 4096);
    short8 a[4], b[4];
    #pragma unroll
    for (int m = 0; m < 4; ++m) {
      int row = wm * 64 + m * 16 + lr;
      a[m] = A8[row * 4 + SWZ(row, ls)];
    }
    #pragma unroll
    for (int n = 0; n < 4; ++n) {
      int row = wn * 64 + n * 16 + lr;
      b[n] = B8[row * 4 + SWZ(row, ls)];
    }
    #pragma unroll
    for (int m = 0; m < 4; ++m)
      #pragma unroll
      for (int n = 0; n < 4; ++n)
        acc[m][n] = MFMA16(a[m], b[n], acc[m][n]);
  }
  #pragma unroll
  for (int m = 0; m < 4; ++m) {
    #pragma unroll
    for (int n = 0; n < 4; ++n) {
      int col = o0 + wn * 64 + n * 16 + lr;
      float bv = bias ? bias[col] : 0.f;
      #pragma unroll
      for (int j = 0; j < 4; ++j) {
        int r = r0 + wm * 64 + m * 16 + ls * 4 + j;
        float v = acc[m][n][j] + bv;
        if (relu) v = fmaxf(v, 0.f);
        C[(long)r * N + col] = v;
        if (Cb) Cb[(long)r * N + col] = f2bf(v);
      }
    }
  }
}

// ---------------- adaptive pool: 13 taps, 1/13 each; bf16 in, bf16 out ----------------
__global__ void k_pool(const short* __restrict__ Xg, short* __restrict__ pooledB) {
  int id = blockIdx.x * 256 + threadIdx.x;   // 3072*64 = 196608 exact
  int row = id >> 6, cg = id & 63;
  int s = row >> 10, bp = row & 1023;
  int b = bp >> 3, p = bp & 7;
  int t0 = (p * 25) >> 1;
  const short8* src = (const short8*)(Xg + (long)((s * 128 + b) * TPAD + t0) * 512) + cg;
  float acc[8] = {};
  #pragma unroll
  for (int j = 0; j < 13; ++j) {
    short8 v = src[j * 64];
    #pragma unroll
    for (int k = 0; k < 8; ++k) acc[k] += bf2f(v[k]);
  }
  short8 o;
  #pragma unroll
  for (int k = 0; k < 8; ++k) o[k] = f2bf(acc[k] * (1.f / 13.f));
  ((short8*)pooledB)[(long)row * 64 + cg] = o;
}

// ---------------- FMA helper ----------------
__device__ __forceinline__ void fma4x4(const float4& a, const float4& b, float acc[4][4]) {
  acc[0][0] = fmaf(a.x, b.x, acc[0][0]);
  acc[0][1] = fmaf(a.x, b.y, acc[0][1]);
  acc[0][2] = fmaf(a.x, b.z, acc[0][2]);
  acc[0][3] = fmaf(a.x, b.w, acc[0][3]);
  acc[1][0] = fmaf(a.y, b.x, acc[1][0]);
  acc[1][1] = fmaf(a.y, b.y, acc[1][1]);
  acc[1][2] = fmaf(a.y, b.z, acc[1][2]);
  acc[1][3] = fmaf(a.y, b.w, acc[1][3]);
  acc[2][0] = fmaf(a.z, b.x, acc[2][0]);
  acc[2][1] = fmaf(a.z, b.y, acc[2][1]);
  acc[2][2] = fmaf(a.z, b.z, acc[2][2]);
  acc[2][3] = fmaf(a.z, b.w, acc[2][3]);
  acc[3][0] = fmaf(a.w, b.x, acc[3][0]);
  acc[3][1] = fmaf(a.w, b.y, acc[3][1]);
  acc[3][2] = fmaf(a.w, b.z, acc[3][2]);
  acc[3][3] = fmaf(a.w, b.w, acc[3][3]);
}

// ---------------- split-K GEMM stage 1: part[z][M][N] partial sums ----------------
__global__ __launch_bounds__(256) void k_gemm_splitk(const float* __restrict__ A,
                                                     const float* __restrict__ B,
                                                     float* __restrict__ part,
                                                     int M, int N, int K,
                                                     int kchunk, int KS, long bgstride) {
  __shared__ float As[32][68];
  __shared__ float Bs[32][68];
  int r0 = blockIdx.x * 64, c0 = blockIdx.y * 64;
  int bz = blockIdx.z;
  int g = bz / KS, zz = bz - g * KS;
  const float* Bg = B + (long)g * bgstride;
  int k0 = zz * kchunk;
  int tid = threadIdx.x, tc = tid & 15, tr = tid >> 4;
  float acc[4][4] = {};
  for (int kc = k0; kc < k0 + kchunk; kc += 32) {
    __syncthreads();
    #pragma unroll
    for (int j = 0; j < 8; ++j) {
      int idx = tid + 256 * j;
      int row = idx >> 5, kk = idx & 31;
      As[kk][row] = A[(long)(r0 + row) * K + kc + kk];
      Bs[kk][row] = Bg[(long)(c0 + row) * K + kc + kk];
    }
    __syncthreads();
    #pragma unroll 8
    for (int kk = 0; kk < 32; ++kk) {
      float4 a = *(const float4*)&As[kk][tr * 4];
      float4 b = *(const float4*)&Bs[kk][tc * 4];
      fma4x4(a, b, acc);
    }
  }
  float* P = part + (long)bz * M * N;
  #pragma unroll
  for (int rr = 0; rr < 4; ++rr) {
    int r = r0 + tr * 4 + rr;
    int c = c0 + tc * 4;
    float4 v;
    v.x = acc[rr][0]; v.y = acc[rr][1]; v.z = acc[rr][2]; v.w = acc[rr][3];
    *(float4*)&P[(long)r * N + c] = v;
  }
}

// ---------------- split-K stage 2: C[g][m][n] = act(bias + sum_j part[g*KS+j][m][n]) ----------------
__global__ void k_reduce_act(const float* __restrict__ part, float* __restrict__ C,
                             const float* __restrict__ bias, int N, int MN,
                             int KS, int relu, int total4) {
  int id = blockIdx.x * 256 + threadIdx.x;
  if (id >= total4) return;
  int e = id * 4;
  int g = e / MN;
  int rem = e - g * MN;
  const float* base = part + (long)g * KS * MN + rem;
  float4 s = *(const float4*)base;
  for (int j = 1; j < KS; ++j) {
    float4 v = *(const float4*)(base + (long)j * MN);
    s.x += v.x; s.y += v.y; s.z += v.z; s.w += v.w;
  }
  int c = rem % N;
  s.x += bias[c]; s.y += bias[c + 1]; s.z += bias[c + 2]; s.w += bias[c + 3];
  if (relu) {
    s.x = fmaxf(s.x, 0.f); s.y = fmaxf(s.y, 0.f);
    s.z = fmaxf(s.z, 0.f); s.w = fmaxf(s.w, 0.f);
  }
  *(float4*)&C[(long)g * MN + rem] = s;
}

// ---------------- codebook squared norms ----------------
__global__ void k_cbsq(const float* __restrict__ cb, float* __restrict__ cbsq) {
  __shared__ float sm[256];
  int k = blockIdx.x, tid = threadIdx.x;
  float v = cb[k * 256 + tid];
  sm[tid] = v * v;
  __syncthreads();
  for (int off = 128; off; off >>= 1) { if (tid < off) sm[tid] += sm[tid + off]; __syncthreads(); }
  if (tid == 0) cbsq[k] = sm[0];
}

// ---------------- VQ argmin + gather + commit partial (all 3 segs) ----------------
__global__ __launch_bounds__(256) void k_vq(const float* __restrict__ dot,
                                            const float* __restrict__ cbsq,
                                            const float* __restrict__ ze,
                                            const float* __restrict__ cb,
                                            float* __restrict__ zall,
                                            float* __restrict__ commit_part) {
  __shared__ float sv[256];
  __shared__ int si[256];
  int row = blockIdx.x, tid = threadIdx.x;   // row = s*1024 + b*8 + p
  float best = 3.4e38f; int bi = 0;
  #pragma unroll
  for (int j = 0; j < 4; ++j) {
    int k = tid * 4 + j;
    float d = cbsq[k] - 2.f * dot[(long)row * 1024 + k];
    if (d < best) { best = d; bi = k; }
  }
  sv[tid] = best; si[tid] = bi;
  __syncthreads();
  for (int off = 128; off; off >>= 1) {
    if (tid < off) {
      float o = sv[tid + off]; int oi = si[tid + off];
      if (o < sv[tid] || (o == sv[tid] && oi < si[tid])) { sv[tid] = o; si[tid] = oi; }
    }
    __syncthreads();
  }
  int ks = si[0];
  float zq = cb[ks * 256 + tid];
  float zev = ze[(long)row * 256 + tid];
  int s = row >> 10, bp = row & 1023;
  int b = bp >> 3, p = bp & 7;
  zall[b * 6144 + s * 2048 + p * 256 + tid] = zq;
  float d = zev - zq;
  __syncthreads();
  sv[tid] = d * d;
  __syncthreads();
  for (int off = 128; off; off >>= 1) { if (tid < off) sv[tid] += sv[tid + off]; __syncthreads(); }
  if (tid == 0) commit_part[row] = sv[0];
}

// ---------------- deconv1 collapsed tap-sum weights: S[cls][o][i] ----------------
__global__ void k_buildS(const float* __restrict__ d1w, float* __restrict__ S) {
  int id = blockIdx.x * 256 + threadIdx.x;   // 3*512*512 exact
  int i = id & 511;
  int o = (id >> 9) & 511;
  int cls = id >> 18;
  const float* w = d1w + (i * 512 + o) * 3;
  float v;
  if (cls == 0)      v = w[0] + w[1];
  else if (cls == 1) v = w[0] + w[1] + w[2];
  else               v = w[1] + w[2];
  S[(cls * 512 + o) * 512 + i] = v;
}

// ---------------- transpose d2w [512][4096] -> [4096][512] ----------------
__global__ void k_transpose(const float* __restrict__ src, float* __restrict__ dst) {
  __shared__ float tile[32][33];
  int bx = blockIdx.x, by = blockIdx.y;
  int tx = threadIdx.x & 31, ty = threadIdx.x >> 5;
  #pragma unroll
  for (int j = 0; j < 32; j += 8)
    tile[ty + j][tx] = src[(by * 32 + ty + j) * 4096 + bx * 32 + tx];
  __syncthreads();
  #pragma unroll
  for (int j = 0; j < 32; j += 8)
    dst[(bx * 32 + ty + j) * 512 + by * 32 + tx] = tile[tx][ty + j];
}

// ---------------- logsumexp over each 1024-vocab row ----------------
__global__ __launch_bounds__(256) void k_lse(const float* __restrict__ logits,
                                             float* __restrict__ lse) {
  __shared__ float sm[256];
  int blk = blockIdx.x;                       // cls*512 + b*4 + cb
  int cb_i = blk & 3, b = (blk >> 2) & 127, cls = blk >> 9;
  const float* rp = logits + (cls * 128 + b) * 4096 + cb_i * 1024;
  int tid = threadIdx.x;
  float v0 = rp[tid], v1 = rp[tid + 256], v2 = rp[tid + 512], v3 = rp[tid + 768];
  float m = fmaxf(fmaxf(v0, v1), fmaxf(v2, v3));
  sm[tid] = m; __syncthreads();
  for (int off = 128; off; off >>= 1) { if (tid < off) sm[tid] = fmaxf(sm[tid], sm[tid + off]); __syncthreads(); }
  float gm = sm[0]; __syncthreads();
  float e = expf(v0 - gm) + expf(v1 - gm) + expf(v2 - gm) + expf(v3 - gm);
  sm[tid] = e; __syncthreads();
  for (int off = 128; off; off >>= 1) { if (tid < off) sm[tid] += sm[tid + off]; __syncthreads(); }
  if (tid == 0) lse[blk] = gm + logf(sm[0]);
}

// ---------------- recon nll partial sums ----------------
__global__ void k_recon(const int* __restrict__ tok, const float* __restrict__ logits,
                        const float* __restrict__ lse, float* __restrict__ part) {
  __shared__ float sm[256];
  int id = blockIdx.x * 256 + threadIdx.x;    // 51200 exact
  int cb_i = id & 3;
  int t = (id >> 2) % 100;
  int b = id / 400;
  int tk = tok[id];
  int cls = (t == 0) ? 0 : ((t == 99) ? 2 : 1);
  float val = lse[cls * 512 + b * 4 + cb_i]
            - logits[(cls * 128 + b) * 4096 + cb_i * 1024 + tk];
  int tid = threadIdx.x;
  sm[tid] = val; __syncthreads();
  for (int off = 128; off; off >>= 1) { if (tid < off) sm[tid] += sm[tid + off]; __syncthreads(); }
  if (tid == 0) part[blockIdx.x] = sm[0];
}

// ---------------- final: total = recon_mean + 0.1 * commit_mean_sum ----------------
__global__ void k_final(const float* __restrict__ rpart, const float* __restrict__ cpart,
                        float* __restrict__ out) {
  __shared__ float sm[256];
  __shared__ float rs;
  int tid = threadIdx.x;
  float r = (tid < 200) ? rpart[tid] : 0.f;
  sm[tid] = r; __syncthreads();
  for (int off = 128; off; off >>= 1) { if (tid < off) sm[tid] += sm[tid + off]; __syncthreads(); }
  if (tid == 0) rs = sm[0];
  __syncthreads();
  float c = 0.f;
  #pragma unroll
  for (int j = 0; j < 12; ++j) c += cpart[tid + 256 * j];
  sm[tid] = c; __syncthreads();
  for (int off = 128; off; off >>= 1) { if (tid < off) sm[tid] += sm[tid + off]; __syncthreads(); }
  if (tid == 0) out[0] = rs / 51200.f + 0.1f * (sm[0] / 262144.f);
}

extern "C" void kernel_launch(void* const* d_in, const int* in_sizes, int n_in,
                              void* d_out, int out_size, void* d_ws, size_t ws_size,
                              hipStream_t stream) {
  const int*   tok_prev = (const int*)d_in[0];
  const int*   tok_curr = (const int*)d_in[1];
  const int*   tok_next = (const int*)d_in[2];
  const float* emb  = (const float*)d_in[3];
  const float* c1w  = (const float*)d_in[4];
  const float* c1b  = (const float*)d_in[5];
  const float* c2w  = (const float*)d_in[6];
  const float* c2b  = (const float*)d_in[7];
  const float* c3w  = (const float*)d_in[8];
  const float* c3b  = (const float*)d_in[9];
  const float* cbk  = (const float*)d_in[10];
  const float* fc1w = (const float*)d_in[11];
  const float* fc1b = (const float*)d_in[12];
  const float* fc2w = (const float*)d_in[13];
  const float* fc2b = (const float*)d_in[14];
  const float* d1w  = (const float*)d_in[15];
  const float* d1b  = (const float*)d_in[16];
  const float* d2w  = (const float*)d_in[17];
  const float* d2b  = (const float*)d_in[18];

  // ---- workspace layout (f32 word offsets) ----
  float* ws = (float*)d_ws;
  short* XbS = (short*)ws;                          // bf16 (NROW+2)x512, guard row0
  short* YbS = (short*)(ws + 10224128);
  float* fp  = ws + 2 * 10224128;
  short* Wb1    = (short*)fp;                       // 786,432 sh = 393,216 w
  short* Wb2    = (short*)(fp + 393216);
  short* c3wB   = (short*)(fp + 786432);            // 131,072 sh = 65,536 w
  short* cbkB   = (short*)(fp + 851968);            // 262,144 sh = 131,072 w
  short* pooledB= (short*)(fp + 983040);            // 1,572,864 sh = 786,432 w
  float* ze     = fp + 1769472;                     // 3072*256 = 786,432
  short* zeB    = (short*)(fp + 2555904);           // 786,432 sh = 393,216 w
  float* dotb   = fp + 2949120;                     // 3,145,728 (also split-K partials)
  float* cbsq   = dotb + 3145728;                   //     1,024
  float* zall   = cbsq + 1024;                      //   786,432
  float* cpart  = zall + 786432;                    //     3,072
  float* h1     = cpart + 3072;                     //    65,536
  float* h2     = h1 + 65536;                       //    65,536
  float* S      = h2 + 65536;                       //   786,432
  float* h2c    = S + 786432;                       //   196,608
  float* d2wT   = h2c + 196608;                     // 2,097,152
  float* logitsb= d2wT + 2097152;                   // 1,572,864
  float* lseb   = logitsb + 1572864;
  float* rpart  = lseb + 1536;
  // total ~32.1M words ~128.5 MB

  const short* X = XbS + 512;
  short* Yv = YbS + 512;
  float* part = dotb;   // dot consumed by k_vq before the decoder runs

  // ---- prep (independent of tokens) ----
  k_guard    <<<8, 256, 0, stream>>>(XbS, YbS);
  k_cvt      <<<7680, 256, 0, stream>>>(c1w, c2w, c3w, cbk, Wb1, Wb2, c3wB, cbkB);
  k_buildS   <<<3072, 256, 0, stream>>>(d1w, S);
  k_transpose<<<dim3(128, 16), 256, 0, stream>>>(d2w, d2wT);
  k_cbsq     <<<1024, 256, 0, stream>>>(cbk, cbsq);

  // ---- encoder, all 3 segments batched ----
  k_embed     <<<9984, 256, 0, stream>>>(tok_prev, tok_curr, tok_next, emb, XbS);
  k_conv3_mfma<<<dim3(312, 4), 256, 0, stream>>>(X, Wb1, c1b, Yv);
  k_conv3_mfma<<<dim3(312, 4), 256, 0, stream>>>((const short*)Yv, Wb2, c2b, (short*)X);
  k_pool      <<<768, 256, 0, stream>>>(X, pooledB);
  k_gemm_mfma <<<dim3(24, 2), 256, 0, stream>>>(pooledB, c3wB, ze, zeB, c3b, 512, 256, 0);
  k_gemm_mfma <<<dim3(24, 8), 256, 0, stream>>>(zeB, cbkB, dotb, nullptr, nullptr, 256, 1024, 0);
  k_vq        <<<3072, 256, 0, stream>>>(dotb, cbsq, ze, cbk, zall, cpart);

  // ---- decoder (split-K two-stage for parallelism) ----
  k_gemm_splitk<<<dim3(2, 8, 16), 256, 0, stream>>>(zall, fc1w, part, 128, 512, 6144, 384, 16, 0);
  k_reduce_act <<<64, 256, 0, stream>>>(part, h1, fc1b, 512, 65536, 16, 1, 16384);
  k_gemm_splitk<<<dim3(2, 8, 4), 256, 0, stream>>>(h1, fc2w, part, 128, 512, 512, 128, 4, 0);
  k_reduce_act <<<64, 256, 0, stream>>>(part, h2, fc2b, 512, 65536, 4, 1, 16384);
  k_gemm_splitk<<<dim3(2, 8, 12), 256, 0, stream>>>(h2, S, part, 128, 512, 512, 128, 4, 262144);
  k_reduce_act <<<192, 256, 0, stream>>>(part, h2c, d1b, 512, 65536, 4, 1, 49152);
  k_gemm_splitk<<<dim3(6, 64, 2), 256, 0, stream>>>(h2c, d2wT, part, 384, 4096, 512, 256, 2, 0);
  k_reduce_act <<<1536, 256, 0, stream>>>(part, logitsb, d2b, 4096, 1572864, 2, 0, 393216);

  k_lse  <<<1536, 256, 0, stream>>>(logitsb, lseb);
  k_recon<<<200, 256, 0, stream>>>(tok_curr, logitsb, lseb, rpart);
  k_final<<<1, 256, 0, stream>>>(rpart, cpart, (float*)d_out);
}

// Round 5
// 294.024 us; speedup vs baseline: 14.0056x; 1.1744x over previous
//
#include <hip/hip_runtime.h>
#include <math.h>

#define B_    128
#define T_    100
#define TPAD  104
#define CB_   4
#define EMB_  128
#define NROW  39936          // 3*128*104 padded rows (all 3 segments)

typedef __attribute__((ext_vector_type(8))) short short8;
typedef __attribute__((ext_vector_type(4))) short short4v;
typedef __attribute__((ext_vector_type(4))) float f32x4;

__device__ __forceinline__ short f2bf(float x) {
  unsigned u = __builtin_bit_cast(unsigned, x);
  u += 0x7fffu + ((u >> 16) & 1u);
  return (short)(u >> 16);
}
__device__ __forceinline__ float bf2f(short s) {
  unsigned u = ((unsigned)(unsigned short)s) << 16;
  return __builtin_bit_cast(float, u);
}

#define GLOAD_LDS(g, l) __builtin_amdgcn_global_load_lds( \
    (const __attribute__((address_space(1))) void*)(g),   \
    (__attribute__((address_space(3))) void*)(l), 16, 0, 0)

#define MFMA16(a, b, c) __builtin_amdgcn_mfma_f32_16x16x32_bf16(a, b, c, 0, 0, 0)
#define SWZ(row, slot) (((slot) + ((row) >> 1)) & 3)

// ================ mega-prep: guards + all weight conversions + cbsq ================
// segments (by flat id): [0,2048) guards; [2048,1574912) conv W; [.. ,1705984) c3wB;
// [..,1968128) cbkB; [..,5113856) fc1wB; [..,5376000) fc2wB; [..,6162432) SB;
// blocks [24072,26120) d2w transpose; blocks [26120,26376) cbsq. grid = 26376.
__global__ void k_prep(const float* __restrict__ c1w, const float* __restrict__ c2w,
                       const float* __restrict__ c3w, const float* __restrict__ cbk,
                       const float* __restrict__ fc1w, const float* __restrict__ fc2w,
                       const float* __restrict__ d1w, const float* __restrict__ d2w,
                       short* __restrict__ XbS, short* __restrict__ YbS,
                       short* __restrict__ Wb1, short* __restrict__ Wb2,
                       short* __restrict__ c3wB, short* __restrict__ cbkB,
                       short* __restrict__ fc1wB, short* __restrict__ fc2wB,
                       short* __restrict__ SB, short* __restrict__ d2wTB,
                       float* __restrict__ cbsq) {
  __shared__ float tile[32][33];
  int bid = blockIdx.x;
  int id = bid * 256 + threadIdx.x;
  if (bid < 24072) {
    if (id < 2048) {
      short* buf = (id >> 10) ? YbS : XbS;
      int rem = id & 1023;
      int row = rem >> 9, c = rem & 511;
      long off = row ? ((long)(NROW + 1) * 512 + c) : c;
      buf[off] = 0;
    } else if (id < 1574912) {
      int local = id - 2048;
      const float* w = (local < 786432) ? c1w : c2w;
      short* o = (local < 786432) ? Wb1 : Wb2;
      int l2 = (local < 786432) ? local : local - 786432;
      int i = l2 & 511, oo = (l2 >> 9) & 511, tap = l2 >> 18;
      o[l2] = f2bf(w[oo * 1536 + i * 3 + tap]);
    } else if (id < 1705984) {
      int l = id - 1574912;
      c3wB[l] = f2bf(c3w[l]);
    } else if (id < 1968128) {
      int l = id - 1705984;
      cbkB[l] = f2bf(cbk[l]);
    } else if (id < 5113856) {
      int l = id - 1968128;
      fc1wB[l] = f2bf(fc1w[l]);
    } else if (id < 5376000) {
      int l = id - 5113856;
      fc2wB[l] = f2bf(fc2w[l]);
    } else {
      int l = id - 5376000;          // 3*512*512
      int i = l & 511, o = (l >> 9) & 511, cls = l >> 18;
      const float* w = d1w + (i * 512 + o) * 3;
      float v;
      if (cls == 0)      v = w[0] + w[1];
      else if (cls == 1) v = w[0] + w[1] + w[2];
      else               v = w[1] + w[2];
      SB[(cls * 512 + o) * 512 + i] = f2bf(v);
    }
  } else if (bid < 26120) {
    // transpose d2w [512][4096] -> bf16 [4096][512]
    int blk = bid - 24072;            // 0..2047
    int bx = blk & 127, by = blk >> 7;
    int tx = threadIdx.x & 31, ty = threadIdx.x >> 5;
    #pragma unroll
    for (int j = 0; j < 32; j += 8)
      tile[ty + j][tx] = d2w[(by * 32 + ty + j) * 4096 + bx * 32 + tx];
    __syncthreads();
    #pragma unroll
    for (int j = 0; j < 32; j += 8)
      d2wTB[(bx * 32 + ty + j) * 512 + by * 32 + tx] = f2bf(tile[tx][ty + j]);
  } else {
    // cbsq: one 64-lane wave per 4 rows segment -> row = idx>>6
    int idx = (bid - 26120) * 256 + threadIdx.x;   // 0..65535
    int row = idx >> 6, lane = threadIdx.x & 63;
    float4 v = *(const float4*)&cbk[row * 256 + lane * 4];
    float s = v.x * v.x + v.y * v.y + v.z * v.z + v.w * v.w;
    #pragma unroll
    for (int m = 1; m < 64; m <<= 1) s += __shfl_xor(s, m);
    if (lane == 0) cbsq[row] = s;
  }
}

// ================ embedding gather (all 3 segs) -> bf16 padded buffer ================
__global__ void k_embed(const int* __restrict__ t0, const int* __restrict__ t1,
                        const int* __restrict__ t2, const float* __restrict__ emb,
                        short* __restrict__ x) {   // x = raw base (guard at row 0)
  int id = blockIdx.x * 256 + threadIdx.x;      // NROW*64 = 2,555,904 exact
  int c8 = id & 63;
  int row = id >> 6;
  int t = row % TPAD;
  int sb = row / TPAD;
  int b = sb & 127, s = sb >> 7;
  short8 v = {};
  if (t < T_) {
    const int* tok = (s == 0) ? t0 : (s == 1) ? t1 : t2;
    int tk = tok[(b * T_ + t) * CB_ + (c8 >> 4)];
    const float* e = emb + tk * EMB_ + (c8 & 15) * 8;
    float4 f0 = *(const float4*)e;
    float4 f1 = *(const float4*)(e + 4);
    v[0] = f2bf(f0.x); v[1] = f2bf(f0.y); v[2] = f2bf(f0.z); v[3] = f2bf(f0.w);
    v[4] = f2bf(f1.x); v[5] = f2bf(f1.y); v[6] = f2bf(f1.z); v[7] = f2bf(f1.w);
  }
  ((short8*)x)[(long)(row + 1) * 64 + c8] = v;
}

// ================ 3-tap conv via bf16 MFMA, global_load_lds staging ================
__global__ __launch_bounds__(256) void k_conv3_mfma(const short* __restrict__ X,
                                                    const short* __restrict__ Wb,
                                                    const float* __restrict__ bias,
                                                    short* __restrict__ Y) {
  __shared__ short sm[16896];     // A: 144 rows x 32 (4608) + B: 3*128 rows x 32 (12288)
  int r0 = blockIdx.y * 128;      // grid (4, 312): o-blocks adjacent in dispatch order
  int o0 = blockIdx.x * 128;
  int tid = threadIdx.x;
  int lane = tid & 63, wid = tid >> 6;
  int wm = wid >> 1, wn = wid & 1;
  int ls = lane >> 4, lr = lane & 15;
  int g = ((lane & 3) - ((lane >> 3) & 3)) & 3;
  long laneoff = (long)(lane >> 2) * 512 + g * 8;

  const short* gp[9];
  const short* lp[9];
  #pragma unroll
  for (int i = 0; i < 9; ++i) {
    int q = wid + 4 * i;
    if (q < 33) {
      long base;
      const short* src;
      if (q < 9) { src = X; base = (long)(r0 - 1 + 16 * q) * 512; }
      else {
        int b = q - 9, tap = b >> 3, j = b & 7;
        src = Wb; base = (long)(tap * 512 + o0 + 16 * j) * 512;
      }
      gp[i] = src + base + laneoff;
      lp[i] = sm + q * 512;
    }
  }

  f32x4 acc[4][4] = {};
  for (int kc = 0; kc < 512; kc += 32) {
    __syncthreads();
    #pragma unroll
    for (int i = 0; i < 9; ++i) {
      int q = wid + 4 * i;
      if (q < 33) {
        GLOAD_LDS(gp[i], lp[i]);
        gp[i] += 32;
      }
    }
    __syncthreads();
    const short8* A8 = (const short8*)sm;
    const short8* B8 = (const short8*)(sm + 4608);
    #pragma unroll
    for (int tap = 0; tap < 3; ++tap) {
      short8 a[4], b[4];
      #pragma unroll
      for (int m = 0; m < 4; ++m) {
        int row = wm * 64 + m * 16 + lr + tap;
        a[m] = A8[row * 4 + SWZ(row, ls)];
      }
      #pragma unroll
      for (int n = 0; n < 4; ++n) {
        int row = wn * 64 + n * 16 + lr;
        b[n] = B8[(tap * 128 + row) * 4 + SWZ(row, ls)];
      }
      #pragma unroll
      for (int m = 0; m < 4; ++m)
        #pragma unroll
        for (int n = 0; n < 4; ++n)
          acc[m][n] = MFMA16(a[m], b[n], acc[m][n]);
    }
  }
  #pragma unroll
  for (int m = 0; m < 4; ++m) {
    #pragma unroll
    for (int n = 0; n < 4; ++n) {
      int col = o0 + wn * 64 + n * 16 + lr;
      float bv = bias[col];
      #pragma unroll
      for (int j = 0; j < 4; ++j) {
        int r = r0 + wm * 64 + m * 16 + ls * 4 + j;
        int t = r % TPAD;
        float v = (t < T_) ? fmaxf(acc[m][n][j] + bv, 0.f) : 0.f;
        Y[(long)r * 512 + col] = f2bf(v);
      }
    }
  }
}

// ================ bf16 MFMA GEMM (full-K): C = act(A@B^T + bias) ================
__global__ __launch_bounds__(256) void k_gemm_mfma(const short* __restrict__ A,
                                                   const short* __restrict__ B,
                                                   float* __restrict__ C,
                                                   short* __restrict__ Cb,
                                                   const float* __restrict__ bias,
                                                   int K, int N, int relu) {
  __shared__ short sm[8192];
  int r0 = blockIdx.x * 128;
  int o0 = blockIdx.y * 128;
  int tid = threadIdx.x;
  int lane = tid & 63, wid = tid >> 6;
  int wm = wid >> 1, wn = wid & 1;
  int ls = lane >> 4, lr = lane & 15;
  int g = ((lane & 3) - ((lane >> 3) & 3)) & 3;
  long laneoff = (long)(lane >> 2) * K + g * 8;

  const short* gp[4];
  const short* lp[4];
  #pragma unroll
  for (int i = 0; i < 4; ++i) {
    int q = wid + 4 * i;
    const short* src;
    long base;
    if (q < 8) { src = A; base = (long)(r0 + 16 * q) * K; }
    else       { src = B; base = (long)(o0 + 16 * (q - 8)) * K; }
    gp[i] = src + base + laneoff;
    lp[i] = sm + q * 512;
  }

  f32x4 acc[4][4] = {};
  for (int kc = 0; kc < K; kc += 32) {
    __syncthreads();
    #pragma unroll
    for (int i = 0; i < 4; ++i) {
      GLOAD_LDS(gp[i], lp[i]);
      gp[i] += 32;
    }
    __syncthreads();
    const short8* A8 = (const short8*)sm;
    const short8* B8 = (const short8*)(sm + 4096);
    short8 a[4], b[4];
    #pragma unroll
    for (int m = 0; m < 4; ++m) {
      int row = wm * 64 + m * 16 + lr;
      a[m] = A8[row * 4 + SWZ(row, ls)];
    }
    #pragma unroll
    for (int n = 0; n < 4; ++n) {
      int row = wn * 64 + n * 16 + lr;
      b[n] = B8[row * 4 + SWZ(row, ls)];
    }
    #pragma unroll
    for (int m = 0; m < 4; ++m)
      #pragma unroll
      for (int n = 0; n < 4; ++n)
        acc[m][n] = MFMA16(a[m], b[n], acc[m][n]);
  }
  #pragma unroll
  for (int m = 0; m < 4; ++m) {
    #pragma unroll
    for (int n = 0; n < 4; ++n) {
      int col = o0 + wn * 64 + n * 16 + lr;
      float bv = bias ? bias[col] : 0.f;
      #pragma unroll
      for (int j = 0; j < 4; ++j) {
        int r = r0 + wm * 64 + m * 16 + ls * 4 + j;
        float v = acc[m][n][j] + bv;
        if (relu) v = fmaxf(v, 0.f);
        C[(long)r * N + col] = v;
        if (Cb) Cb[(long)r * N + col] = f2bf(v);
      }
    }
  }
}

// ================ bf16 MFMA split-K stage 1: part[bz][M][N] ================
// grid (M/128, N/128, G*KS); g = bz/KS selects B + g*bgstride; chunk zz = bz%KS.
__global__ __launch_bounds__(256) void k_gemm_mfma_sk(const short* __restrict__ A,
                                                      const short* __restrict__ B,
                                                      float* __restrict__ part,
                                                      int M, int N, int K,
                                                      int kchunk, int KS, long bgstride) {
  __shared__ short sm[8192];
  int r0 = blockIdx.x * 128;
  int o0 = blockIdx.y * 128;
  int bz = blockIdx.z;
  int g = bz / KS, zz = bz - g * KS;
  const short* Bg = B + (long)g * bgstride;
  int k0 = zz * kchunk;
  int tid = threadIdx.x;
  int lane = tid & 63, wid = tid >> 6;
  int wm = wid >> 1, wn = wid & 1;
  int ls = lane >> 4, lr = lane & 15;
  int gsl = ((lane & 3) - ((lane >> 3) & 3)) & 3;
  long laneoff = (long)(lane >> 2) * K + gsl * 8 + k0;

  const short* gp[4];
  const short* lp[4];
  #pragma unroll
  for (int i = 0; i < 4; ++i) {
    int q = wid + 4 * i;
    const short* src;
    long base;
    if (q < 8) { src = A;  base = (long)(r0 + 16 * q) * K; }
    else       { src = Bg; base = (long)(o0 + 16 * (q - 8)) * K; }
    gp[i] = src + base + laneoff;
    lp[i] = sm + q * 512;
  }

  f32x4 acc[4][4] = {};
  for (int kc = 0; kc < kchunk; kc += 32) {
    __syncthreads();
    #pragma unroll
    for (int i = 0; i < 4; ++i) {
      GLOAD_LDS(gp[i], lp[i]);
      gp[i] += 32;
    }
    __syncthreads();
    const short8* A8 = (const short8*)sm;
    const short8* B8 = (const short8*)(sm + 4096);
    short8 a[4], b[4];
    #pragma unroll
    for (int m = 0; m < 4; ++m) {
      int row = wm * 64 + m * 16 + lr;
      a[m] = A8[row * 4 + SWZ(row, ls)];
    }
    #pragma unroll
    for (int n = 0; n < 4; ++n) {
      int row = wn * 64 + n * 16 + lr;
      b[n] = B8[row * 4 + SWZ(row, ls)];
    }
    #pragma unroll
    for (int m = 0; m < 4; ++m)
      #pragma unroll
      for (int n = 0; n < 4; ++n)
        acc[m][n] = MFMA16(a[m], b[n], acc[m][n]);
  }
  float* P = part + (long)bz * M * N;
  #pragma unroll
  for (int m = 0; m < 4; ++m) {
    #pragma unroll
    for (int n = 0; n < 4; ++n) {
      int col = o0 + wn * 64 + n * 16 + lr;
      #pragma unroll
      for (int j = 0; j < 4; ++j) {
        int r = r0 + wm * 64 + m * 16 + ls * 4 + j;
        P[(long)r * N + col] = acc[m][n][j];
      }
    }
  }
}

// ================ split-K stage 2 -> bf16: Cb[g][m][n] = act(bias + sum partials) ================
__global__ void k_reduce_bf16(const float* __restrict__ part, short* __restrict__ Cb,
                              const float* __restrict__ bias, int N, int MN,
                              int KS, int relu, int total4) {
  int id = blockIdx.x * 256 + threadIdx.x;
  if (id >= total4) return;
  int e = id * 4;
  int g = e / MN;
  int rem = e - g * MN;
  const float* base = part + (long)g * KS * MN + rem;
  float4 s = *(const float4*)base;
  for (int j = 1; j < KS; ++j) {
    float4 v = *(const float4*)(base + (long)j * MN);
    s.x += v.x; s.y += v.y; s.z += v.z; s.w += v.w;
  }
  int c = rem % N;
  s.x += bias[c]; s.y += bias[c + 1]; s.z += bias[c + 2]; s.w += bias[c + 3];
  if (relu) {
    s.x = fmaxf(s.x, 0.f); s.y = fmaxf(s.y, 0.f);
    s.z = fmaxf(s.z, 0.f); s.w = fmaxf(s.w, 0.f);
  }
  short4v o;
  o[0] = f2bf(s.x); o[1] = f2bf(s.y); o[2] = f2bf(s.z); o[3] = f2bf(s.w);
  *(short4v*)&Cb[(long)g * MN + rem] = o;
}

// ================ adaptive pool: 13 taps, 1/13 each; bf16 in/out ================
__global__ void k_pool(const short* __restrict__ Xg, short* __restrict__ pooledB) {
  int id = blockIdx.x * 256 + threadIdx.x;   // 3072*64 = 196608 exact
  int row = id >> 6, cg = id & 63;
  int s = row >> 10, bp = row & 1023;
  int b = bp >> 3, p = bp & 7;
  int t0 = (p * 25) >> 1;
  const short8* src = (const short8*)(Xg + (long)((s * 128 + b) * TPAD + t0) * 512) + cg;
  float acc[8] = {};
  #pragma unroll
  for (int j = 0; j < 13; ++j) {
    short8 v = src[j * 64];
    #pragma unroll
    for (int k = 0; k < 8; ++k) acc[k] += bf2f(v[k]);
  }
  short8 o;
  #pragma unroll
  for (int k = 0; k < 8; ++k) o[k] = f2bf(acc[k] * (1.f / 13.f));
  ((short8*)pooledB)[(long)row * 64 + cg] = o;
}

// ================ VQ argmin + bf16 gather + commit partial ================
__global__ __launch_bounds__(256) void k_vq(const float* __restrict__ dot,
                                            const float* __restrict__ cbsq,
                                            const float* __restrict__ ze,
                                            const float* __restrict__ cb,
                                            const short* __restrict__ cbkB,
                                            short* __restrict__ zallB,
                                            float* __restrict__ commit_part) {
  __shared__ float sv[256];
  __shared__ int si[256];
  int row = blockIdx.x, tid = threadIdx.x;   // row = s*1024 + b*8 + p
  float best = 3.4e38f; int bi = 0;
  #pragma unroll
  for (int j = 0; j < 4; ++j) {
    int k = tid * 4 + j;
    float d = cbsq[k] - 2.f * dot[(long)row * 1024 + k];
    if (d < best) { best = d; bi = k; }
  }
  sv[tid] = best; si[tid] = bi;
  __syncthreads();
  for (int off = 128; off; off >>= 1) {
    if (tid < off) {
      float o = sv[tid + off]; int oi = si[tid + off];
      if (o < sv[tid] || (o == sv[tid] && oi < si[tid])) { sv[tid] = o; si[tid] = oi; }
    }
    __syncthreads();
  }
  int ks = si[0];
  float zq = cb[ks * 256 + tid];
  float zev = ze[(long)row * 256 + tid];
  int s = row >> 10, bp = row & 1023;
  int b = bp >> 3, p = bp & 7;
  zallB[b * 6144 + s * 2048 + p * 256 + tid] = cbkB[ks * 256 + tid];
  float d = zev - zq;
  __syncthreads();
  sv[tid] = d * d;
  __syncthreads();
  for (int off = 128; off; off >>= 1) { if (tid < off) sv[tid] += sv[tid + off]; __syncthreads(); }
  if (tid == 0) commit_part[row] = sv[0];
}

// ================ fused: logits-partials reduce + logsumexp + NLL gather ================
// grid 1536: blk = cls*512 + b*4 + cb. part: [2][384][4096], m = cls*128+b.
__global__ __launch_bounds__(256) void k_logits_lse_recon(const float* __restrict__ part,
                                                          const float* __restrict__ d2b,
                                                          const int* __restrict__ tok,
                                                          float* __restrict__ rpart2) {
  __shared__ float row[1024];
  __shared__ float sm[256];
  int blk = blockIdx.x;
  int cb_i = blk & 3, b = (blk >> 2) & 127, cls = blk >> 9;
  int m = cls * 128 + b;
  const float* p0 = part + (long)m * 4096 + cb_i * 1024;
  const float* p1 = p0 + (long)384 * 4096;
  const float* bb = d2b + cb_i * 1024;
  int tid = threadIdx.x;
  float v[4];
  #pragma unroll
  for (int j = 0; j < 4; ++j) {
    int c = tid + 256 * j;
    v[j] = p0[c] + p1[c] + bb[c];
    row[c] = v[j];
  }
  float mx = fmaxf(fmaxf(v[0], v[1]), fmaxf(v[2], v[3]));
  sm[tid] = mx; __syncthreads();
  for (int off = 128; off; off >>= 1) { if (tid < off) sm[tid] = fmaxf(sm[tid], sm[tid + off]); __syncthreads(); }
  float gm = sm[0]; __syncthreads();
  float e = expf(v[0] - gm) + expf(v[1] - gm) + expf(v[2] - gm) + expf(v[3] - gm);
  sm[tid] = e; __syncthreads();
  for (int off = 128; off; off >>= 1) { if (tid < off) sm[tid] += sm[tid + off]; __syncthreads(); }
  float lse = gm + logf(sm[0]);
  __syncthreads();
  // token gather: cls0 -> t=0; cls1 -> t=1..98; cls2 -> t=99
  float val = 0.f;
  if (cls == 1) {
    if (tid < 98) {
      int tk = tok[(b * T_ + tid + 1) * CB_ + cb_i];
      val = lse - row[tk];
    }
  } else if (tid == 0) {
    int t = (cls == 0) ? 0 : 99;
    int tk = tok[(b * T_ + t) * CB_ + cb_i];
    val = lse - row[tk];
  }
  sm[tid] = val; __syncthreads();
  for (int off = 128; off; off >>= 1) { if (tid < off) sm[tid] += sm[tid + off]; __syncthreads(); }
  if (tid == 0) rpart2[blk] = sm[0];
}

// ================ final: total = recon_mean + 0.1 * commit_mean_sum ================
__global__ void k_final(const float* __restrict__ rpart2, const float* __restrict__ cpart,
                        float* __restrict__ out) {
  __shared__ float sm[256];
  __shared__ float rs;
  int tid = threadIdx.x;
  float r = 0.f;
  #pragma unroll
  for (int j = 0; j < 6; ++j) r += rpart2[tid + 256 * j];
  sm[tid] = r; __syncthreads();
  for (int off = 128; off; off >>= 1) { if (tid < off) sm[tid] += sm[tid + off]; __syncthreads(); }
  if (tid == 0) rs = sm[0];
  __syncthreads();
  float c = 0.f;
  #pragma unroll
  for (int j = 0; j < 12; ++j) c += cpart[tid + 256 * j];
  sm[tid] = c; __syncthreads();
  for (int off = 128; off; off >>= 1) { if (tid < off) sm[tid] += sm[tid + off]; __syncthreads(); }
  if (tid == 0) out[0] = rs / 51200.f + 0.1f * (sm[0] / 262144.f);
}

extern "C" void kernel_launch(void* const* d_in, const int* in_sizes, int n_in,
                              void* d_out, int out_size, void* d_ws, size_t ws_size,
                              hipStream_t stream) {
  const int*   tok_prev = (const int*)d_in[0];
  const int*   tok_curr = (const int*)d_in[1];
  const int*   tok_next = (const int*)d_in[2];
  const float* emb  = (const float*)d_in[3];
  const float* c1w  = (const float*)d_in[4];
  const float* c1b  = (const float*)d_in[5];
  const float* c2w  = (const float*)d_in[6];
  const float* c2b  = (const float*)d_in[7];
  const float* c3w  = (const float*)d_in[8];
  const float* c3b  = (const float*)d_in[9];
  const float* cbk  = (const float*)d_in[10];
  const float* fc1w = (const float*)d_in[11];
  const float* fc1b = (const float*)d_in[12];
  const float* fc2w = (const float*)d_in[13];
  const float* fc2b = (const float*)d_in[14];
  const float* d1w  = (const float*)d_in[15];
  const float* d1b  = (const float*)d_in[16];
  const float* d2w  = (const float*)d_in[17];
  const float* d2b  = (const float*)d_in[18];

  // ---- workspace layout (f32 word offsets) ----
  float* ws = (float*)d_ws;
  short* XbS = (short*)ws;                          // bf16 (NROW+2)x512, guard row0
  short* YbS = (short*)(ws + 10224128);
  float* fp  = ws + 2 * 10224128;
  short* Wb1    = (short*)fp;                       // 393,216 w
  short* Wb2    = (short*)(fp + 393216);            // 393,216 w
  short* c3wB   = (short*)(fp + 786432);            //  65,536 w
  short* cbkB   = (short*)(fp + 851968);            // 131,072 w
  short* pooledB= (short*)(fp + 983040);            // 786,432 w
  float* ze     = fp + 1769472;                     // 786,432 w
  short* zeB    = (short*)(fp + 2555904);           // 393,216 w
  short* fc1wB  = (short*)(fp + 2949120);           // 1,572,864 w
  short* fc2wB  = (short*)(fp + 4521984);           // 131,072 w
  short* SB     = (short*)(fp + 4653056);           // 393,216 w
  short* d2wTB  = (short*)(fp + 5046272);           // 1,048,576 w
  float* dotb   = fp + 6094848;                     // 3,145,728 w (dot + split-K partials)
  float* cbsq   = dotb + 3145728;                   //     1,024
  short* zallB  = (short*)(cbsq + 1024);            // 393,216 w
  float* cpart  = cbsq + 1024 + 393216;             //     3,072
  short* h1B    = (short*)(cpart + 3072);           //  32,768 w
  short* h2B    = (short*)(cpart + 35840);          //  32,768 w
  short* h2cB   = (short*)(cpart + 68608);          //  98,304 w
  float* rpart2 = cpart + 166912;                   //     1,536
  // total ~30.3M words ~121 MB

  const short* X = XbS + 512;
  short* Yv = YbS + 512;
  float* part = dotb;   // dot consumed by k_vq before the decoder runs

  // ---- prep (all weight conversions, guards, cbsq) ----
  k_prep<<<26376, 256, 0, stream>>>(c1w, c2w, c3w, cbk, fc1w, fc2w, d1w, d2w,
                                    XbS, YbS, Wb1, Wb2, c3wB, cbkB, fc1wB, fc2wB,
                                    SB, d2wTB, cbsq);

  // ---- encoder, all 3 segments batched ----
  k_embed     <<<9984, 256, 0, stream>>>(tok_prev, tok_curr, tok_next, emb, XbS);
  k_conv3_mfma<<<dim3(4, 312), 256, 0, stream>>>(X, Wb1, c1b, Yv);
  k_conv3_mfma<<<dim3(4, 312), 256, 0, stream>>>((const short*)Yv, Wb2, c2b, (short*)X);
  k_pool      <<<768, 256, 0, stream>>>(X, pooledB);
  k_gemm_mfma <<<dim3(24, 2), 256, 0, stream>>>(pooledB, c3wB, ze, zeB, c3b, 512, 256, 0);
  k_gemm_mfma <<<dim3(24, 8), 256, 0, stream>>>(zeB, cbkB, dotb, nullptr, nullptr, 256, 1024, 0);
  k_vq        <<<3072, 256, 0, stream>>>(dotb, cbsq, ze, cbk, cbkB, zallB, cpart);

  // ---- decoder: bf16 MFMA split-K ----
  // fc1: M=128 N=512 K=6144, KS=16 x chunk 384
  k_gemm_mfma_sk<<<dim3(1, 4, 16), 256, 0, stream>>>(zallB, fc1wB, part, 128, 512, 6144, 384, 16, 0);
  k_reduce_bf16 <<<64, 256, 0, stream>>>(part, h1B, fc1b, 512, 65536, 16, 1, 16384);
  // fc2: K=512, KS=8 x chunk 64
  k_gemm_mfma_sk<<<dim3(1, 4, 8), 256, 0, stream>>>(h1B, fc2wB, part, 128, 512, 512, 64, 8, 0);
  k_reduce_bf16 <<<64, 256, 0, stream>>>(part, h2B, fc2b, 512, 65536, 8, 1, 16384);
  // deconv1 collapsed: 3 groups x KS=8 x chunk 64
  k_gemm_mfma_sk<<<dim3(1, 4, 24), 256, 0, stream>>>(h2B, SB, part, 128, 512, 512, 64, 8, 262144);
  k_reduce_bf16 <<<192, 256, 0, stream>>>(part, h2cB, d1b, 512, 65536, 8, 1, 49152);
  // logits: M=384 N=4096 K=512, KS=2 x chunk 256 (partials consumed by fused kernel)
  k_gemm_mfma_sk<<<dim3(3, 32, 2), 256, 0, stream>>>(h2cB, d2wTB, part, 384, 4096, 512, 256, 2, 0);
  k_logits_lse_recon<<<1536, 256, 0, stream>>>(part, d2b, tok_curr, rpart2);

  k_final<<<1, 256, 0, stream>>>(rpart2, cpart, (float*)d_out);
}

// Round 6
// 274.465 us; speedup vs baseline: 15.0036x; 1.0713x over previous
//
#include <hip/hip_runtime.h>
#include <math.h>

#define B_    128
#define T_    100
#define TPAD  104
#define CB_   4
#define EMB_  128
#define NROW  39936          // 3*128*104 padded rows (all 3 segments)
#define ZOFF  131072         // zero-row offset in embB (shorts)

typedef __attribute__((ext_vector_type(8))) short short8;
typedef __attribute__((ext_vector_type(4))) short short4v;
typedef __attribute__((ext_vector_type(4))) float f32x4;

__device__ __forceinline__ short f2bf(float x) {
  unsigned u = __builtin_bit_cast(unsigned, x);
  u += 0x7fffu + ((u >> 16) & 1u);
  return (short)(u >> 16);
}
__device__ __forceinline__ float bf2f(short s) {
  unsigned u = ((unsigned)(unsigned short)s) << 16;
  return __builtin_bit_cast(float, u);
}

#define GLOAD_LDS(g, l) __builtin_amdgcn_global_load_lds( \
    (const __attribute__((address_space(1))) void*)(g),   \
    (__attribute__((address_space(3))) void*)(l), 16, 0, 0)

#define MFMA16(a, b, c) __builtin_amdgcn_mfma_f32_16x16x32_bf16(a, b, c, 0, 0, 0)
#define SWZ(row, slot) (((slot) + ((row) >> 1)) & 3)

// ================ mega-prep: guards + embB + all weight conversions + cbsq ================
// flat ids: [0,1024) Y-guards; [1024,132096) embB; [132096,132224) zero-row;
// [132224,1705088) conv W; [..,1836160) c3wB; [..,2098304) cbkB; [..,5244032) fc1wB;
// [..,5506176) fc2wB; [..,6292608) SB.  blocks [24581,26629) d2w transpose;
// [26629,26885) cbsq.  grid = 26885.
__global__ void k_prep(const float* __restrict__ emb,
                       const float* __restrict__ c1w, const float* __restrict__ c2w,
                       const float* __restrict__ c3w, const float* __restrict__ cbk,
                       const float* __restrict__ fc1w, const float* __restrict__ fc2w,
                       const float* __restrict__ d1w, const float* __restrict__ d2w,
                       short* __restrict__ YbS, short* __restrict__ embB,
                       short* __restrict__ Wb1, short* __restrict__ Wb2,
                       short* __restrict__ c3wB, short* __restrict__ cbkB,
                       short* __restrict__ fc1wB, short* __restrict__ fc2wB,
                       short* __restrict__ SB, short* __restrict__ d2wTB,
                       float* __restrict__ cbsq) {
  __shared__ float tile[32][33];
  int bid = blockIdx.x;
  int id = bid * 256 + threadIdx.x;
  if (bid < 24581) {
    if (id < 1024) {
      int row = id >> 9, c = id & 511;
      long off = row ? ((long)(NROW + 1) * 512 + c) : c;
      YbS[off] = 0;
    } else if (id < 132096) {
      int l = id - 1024;
      embB[l] = f2bf(emb[l]);
    } else if (id < 132224) {
      embB[ZOFF + (id - 132096)] = 0;
    } else if (id < 1705088) {
      int local = id - 132224;
      const float* w = (local < 786432) ? c1w : c2w;
      short* o = (local < 786432) ? Wb1 : Wb2;
      int l2 = (local < 786432) ? local : local - 786432;
      int i = l2 & 511, oo = (l2 >> 9) & 511, tap = l2 >> 18;
      o[l2] = f2bf(w[oo * 1536 + i * 3 + tap]);
    } else if (id < 1836160) {
      int l = id - 1705088;
      c3wB[l] = f2bf(c3w[l]);
    } else if (id < 2098304) {
      int l = id - 1836160;
      cbkB[l] = f2bf(cbk[l]);
    } else if (id < 5244032) {
      int l = id - 2098304;
      fc1wB[l] = f2bf(fc1w[l]);
    } else if (id < 5506176) {
      int l = id - 5244032;
      fc2wB[l] = f2bf(fc2w[l]);
    } else if (id < 6292608) {
      int l = id - 5506176;          // 3*512*512
      int i = l & 511, o = (l >> 9) & 511, cls = l >> 18;
      const float* w = d1w + (i * 512 + o) * 3;
      float v;
      if (cls == 0)      v = w[0] + w[1];
      else if (cls == 1) v = w[0] + w[1] + w[2];
      else               v = w[1] + w[2];
      SB[(cls * 512 + o) * 512 + i] = f2bf(v);
    }
  } else if (bid < 26629) {
    int blk = bid - 24581;            // 0..2047
    int bx = blk & 127, by = blk >> 7;
    int tx = threadIdx.x & 31, ty = threadIdx.x >> 5;
    #pragma unroll
    for (int j = 0; j < 32; j += 8)
      tile[ty + j][tx] = d2w[(by * 32 + ty + j) * 4096 + bx * 32 + tx];
    __syncthreads();
    #pragma unroll
    for (int j = 0; j < 32; j += 8)
      d2wTB[(bx * 32 + ty + j) * 512 + by * 32 + tx] = f2bf(tile[tx][ty + j]);
  } else {
    int idx = (bid - 26629) * 256 + threadIdx.x;   // 0..65535
    int row = idx >> 6, lane = threadIdx.x & 63;
    float4 v = *(const float4*)&cbk[row * 256 + lane * 4];
    float s = v.x * v.x + v.y * v.y + v.z * v.z + v.w * v.w;
    #pragma unroll
    for (int m = 1; m < 64; m <<= 1) s += __shfl_xor(s, m);
    if (lane == 0) cbsq[row] = s;
  }
}

// ================ conv1 with fused embedding gather (bf16 MFMA) ================
// A rows gathered from embB via per-lane global_load_lds source; W streamed.
__global__ __launch_bounds__(256) void k_conv1_embed(const int* __restrict__ tok0,
                                                     const int* __restrict__ tok1,
                                                     const int* __restrict__ tok2,
                                                     const short* __restrict__ embB,
                                                     const short* __restrict__ Wb,
                                                     const float* __restrict__ bias,
                                                     short* __restrict__ Y) {
  __shared__ short sm[16896];     // A: 9*16 rows x 32 (4608) + W: 24*16 x 32 (12288)
  int r0 = blockIdx.y * 128;
  int o0 = blockIdx.x * 128;
  int tid = threadIdx.x;
  int lane = tid & 63, wid = tid >> 6;
  int wm = wid >> 1, wn = wid & 1;
  int ls = lane >> 4, lr = lane & 15;
  int g = ((lane & 3) - ((lane >> 3) & 3)) & 3;

  // ---- A gather setup: token-derived source offsets per staged row ----
  int toff[3][4];
  #pragma unroll
  for (int i = 0; i < 3; ++i) {
    int q = wid + 4 * i;
    if (q < 9) {
      int rr = r0 - 1 + 16 * q + (lane >> 2);
      bool ok = (rr >= 0) && (rr < NROW);
      int sb = ok ? (rr / 104) : 0;
      int t = rr - sb * 104;
      ok = ok && (t < T_);
      int b = sb & 127, s = sb >> 7;
      const int* tokp = (s == 0) ? tok0 : (s == 1) ? tok1 : tok2;
      if (ok) {
        int4 tv = *(const int4*)&tokp[(b * T_ + t) * CB_];
        toff[i][0] = tv.x * EMB_; toff[i][1] = tv.y * EMB_;
        toff[i][2] = tv.z * EMB_; toff[i][3] = tv.w * EMB_;
      } else {
        toff[i][0] = toff[i][1] = toff[i][2] = toff[i][3] = ZOFF;
      }
    }
  }
  // ---- W pointers (q = 9..32) ----
  const short* gpw[9];
  short* lpw[9];
  #pragma unroll
  for (int i = 0; i < 9; ++i) {
    int q = wid + 4 * i;
    if (q >= 9 && q < 33) {
      int b = q - 9, tap = b >> 3, jj = b & 7;
      gpw[i] = Wb + (long)(tap * 512 + o0 + 16 * jj) * 512 + (long)(lane >> 2) * 512 + g * 8;
      lpw[i] = sm + q * 512;
    }
  }

  f32x4 acc[4][4] = {};
  #pragma unroll
  for (int cb = 0; cb < 4; ++cb) {
    #pragma unroll
    for (int kk = 0; kk < 4; ++kk) {
      __syncthreads();
      #pragma unroll
      for (int i = 0; i < 3; ++i) {
        int q = wid + 4 * i;
        if (q < 9) GLOAD_LDS(embB + toff[i][cb] + kk * 32 + g * 8, sm + q * 512);
      }
      #pragma unroll
      for (int i = 0; i < 9; ++i) {
        int q = wid + 4 * i;
        if (q >= 9 && q < 33) {
          GLOAD_LDS(gpw[i], lpw[i]);
          gpw[i] += 32;
        }
      }
      __syncthreads();
      const short8* A8 = (const short8*)sm;
      const short8* B8 = (const short8*)(sm + 4608);
      #pragma unroll
      for (int tap = 0; tap < 3; ++tap) {
        short8 a[4], b[4];
        #pragma unroll
        for (int m = 0; m < 4; ++m) {
          int row = wm * 64 + m * 16 + lr + tap;
          a[m] = A8[row * 4 + SWZ(row, ls)];
        }
        #pragma unroll
        for (int n = 0; n < 4; ++n) {
          int row = wn * 64 + n * 16 + lr;
          b[n] = B8[(tap * 128 + row) * 4 + SWZ(row, ls)];
        }
        #pragma unroll
        for (int m = 0; m < 4; ++m)
          #pragma unroll
          for (int n = 0; n < 4; ++n)
            acc[m][n] = MFMA16(a[m], b[n], acc[m][n]);
      }
    }
  }
  #pragma unroll
  for (int m = 0; m < 4; ++m) {
    #pragma unroll
    for (int n = 0; n < 4; ++n) {
      int col = o0 + wn * 64 + n * 16 + lr;
      float bv = bias[col];
      #pragma unroll
      for (int j = 0; j < 4; ++j) {
        int r = r0 + wm * 64 + m * 16 + ls * 4 + j;
        int t = r % TPAD;
        float v = (t < T_) ? fmaxf(acc[m][n][j] + bv, 0.f) : 0.f;
        Y[(long)r * 512 + col] = f2bf(v);
      }
    }
  }
}

// ================ 3-tap conv via bf16 MFMA, global_load_lds staging (conv2) ================
__global__ __launch_bounds__(256) void k_conv3_mfma(const short* __restrict__ X,
                                                    const short* __restrict__ Wb,
                                                    const float* __restrict__ bias,
                                                    short* __restrict__ Y) {
  __shared__ short sm[16896];
  int r0 = blockIdx.y * 128;
  int o0 = blockIdx.x * 128;
  int tid = threadIdx.x;
  int lane = tid & 63, wid = tid >> 6;
  int wm = wid >> 1, wn = wid & 1;
  int ls = lane >> 4, lr = lane & 15;
  int g = ((lane & 3) - ((lane >> 3) & 3)) & 3;
  long laneoff = (long)(lane >> 2) * 512 + g * 8;

  const short* gp[9];
  const short* lp[9];
  #pragma unroll
  for (int i = 0; i < 9; ++i) {
    int q = wid + 4 * i;
    if (q < 33) {
      long base;
      const short* src;
      if (q < 9) { src = X; base = (long)(r0 - 1 + 16 * q) * 512; }
      else {
        int b = q - 9, tap = b >> 3, j = b & 7;
        src = Wb; base = (long)(tap * 512 + o0 + 16 * j) * 512;
      }
      gp[i] = src + base + laneoff;
      lp[i] = sm + q * 512;
    }
  }

  f32x4 acc[4][4] = {};
  for (int kc = 0; kc < 512; kc += 32) {
    __syncthreads();
    #pragma unroll
    for (int i = 0; i < 9; ++i) {
      int q = wid + 4 * i;
      if (q < 33) {
        GLOAD_LDS(gp[i], lp[i]);
        gp[i] += 32;
      }
    }
    __syncthreads();
    const short8* A8 = (const short8*)sm;
    const short8* B8 = (const short8*)(sm + 4608);
    #pragma unroll
    for (int tap = 0; tap < 3; ++tap) {
      short8 a[4], b[4];
      #pragma unroll
      for (int m = 0; m < 4; ++m) {
        int row = wm * 64 + m * 16 + lr + tap;
        a[m] = A8[row * 4 + SWZ(row, ls)];
      }
      #pragma unroll
      for (int n = 0; n < 4; ++n) {
        int row = wn * 64 + n * 16 + lr;
        b[n] = B8[(tap * 128 + row) * 4 + SWZ(row, ls)];
      }
      #pragma unroll
      for (int m = 0; m < 4; ++m)
        #pragma unroll
        for (int n = 0; n < 4; ++n)
          acc[m][n] = MFMA16(a[m], b[n], acc[m][n]);
    }
  }
  #pragma unroll
  for (int m = 0; m < 4; ++m) {
    #pragma unroll
    for (int n = 0; n < 4; ++n) {
      int col = o0 + wn * 64 + n * 16 + lr;
      float bv = bias[col];
      #pragma unroll
      for (int j = 0; j < 4; ++j) {
        int r = r0 + wm * 64 + m * 16 + ls * 4 + j;
        int t = r % TPAD;
        float v = (t < T_) ? fmaxf(acc[m][n][j] + bv, 0.f) : 0.f;
        Y[(long)r * 512 + col] = f2bf(v);
      }
    }
  }
}

// ================ bf16 MFMA GEMM (full-K): C = act(A@B^T + bias) ================
__global__ __launch_bounds__(256) void k_gemm_mfma(const short* __restrict__ A,
                                                   const short* __restrict__ B,
                                                   float* __restrict__ C,
                                                   short* __restrict__ Cb,
                                                   const float* __restrict__ bias,
                                                   int K, int N, int relu) {
  __shared__ short sm[8192];
  int r0 = blockIdx.x * 128;
  int o0 = blockIdx.y * 128;
  int tid = threadIdx.x;
  int lane = tid & 63, wid = tid >> 6;
  int wm = wid >> 1, wn = wid & 1;
  int ls = lane >> 4, lr = lane & 15;
  int g = ((lane & 3) - ((lane >> 3) & 3)) & 3;
  long laneoff = (long)(lane >> 2) * K + g * 8;

  const short* gp[4];
  const short* lp[4];
  #pragma unroll
  for (int i = 0; i < 4; ++i) {
    int q = wid + 4 * i;
    const short* src;
    long base;
    if (q < 8) { src = A; base = (long)(r0 + 16 * q) * K; }
    else       { src = B; base = (long)(o0 + 16 * (q - 8)) * K; }
    gp[i] = src + base + laneoff;
    lp[i] = sm + q * 512;
  }

  f32x4 acc[4][4] = {};
  for (int kc = 0; kc < K; kc += 32) {
    __syncthreads();
    #pragma unroll
    for (int i = 0; i < 4; ++i) {
      GLOAD_LDS(gp[i], lp[i]);
      gp[i] += 32;
    }
    __syncthreads();
    const short8* A8 = (const short8*)sm;
    const short8* B8 = (const short8*)(sm + 4096);
    short8 a[4], b[4];
    #pragma unroll
    for (int m = 0; m < 4; ++m) {
      int row = wm * 64 + m * 16 + lr;
      a[m] = A8[row * 4 + SWZ(row, ls)];
    }
    #pragma unroll
    for (int n = 0; n < 4; ++n) {
      int row = wn * 64 + n * 16 + lr;
      b[n] = B8[row * 4 + SWZ(row, ls)];
    }
    #pragma unroll
    for (int m = 0; m < 4; ++m)
      #pragma unroll
      for (int n = 0; n < 4; ++n)
        acc[m][n] = MFMA16(a[m], b[n], acc[m][n]);
  }
  #pragma unroll
  for (int m = 0; m < 4; ++m) {
    #pragma unroll
    for (int n = 0; n < 4; ++n) {
      int col = o0 + wn * 64 + n * 16 + lr;
      float bv = bias ? bias[col] : 0.f;
      #pragma unroll
      for (int j = 0; j < 4; ++j) {
        int r = r0 + wm * 64 + m * 16 + ls * 4 + j;
        float v = acc[m][n][j] + bv;
        if (relu) v = fmaxf(v, 0.f);
        C[(long)r * N + col] = v;
        if (Cb) Cb[(long)r * N + col] = f2bf(v);
      }
    }
  }
}

// ================ dot GEMM + per-tile argmin partials (fused) ================
// grid (24, 8): 128x128 tile of dist = cbsq[col] - 2*ze.cb; writes per-row (min,idx).
__global__ __launch_bounds__(256) void k_dot_argmin(const short* __restrict__ A,
                                                    const short* __restrict__ B,
                                                    const float* __restrict__ cbsq,
                                                    float* __restrict__ apv,
                                                    int* __restrict__ api) {
  __shared__ short sm[8192];
  __shared__ float svv[128][2];
  __shared__ int sii[128][2];
  const int K = 256;
  int r0 = blockIdx.x * 128;
  int o0 = blockIdx.y * 128;
  int tid = threadIdx.x;
  int lane = tid & 63, wid = tid >> 6;
  int wm = wid >> 1, wn = wid & 1;
  int ls = lane >> 4, lr = lane & 15;
  int g = ((lane & 3) - ((lane >> 3) & 3)) & 3;
  long laneoff = (long)(lane >> 2) * K + g * 8;

  const short* gp[4];
  const short* lp[4];
  #pragma unroll
  for (int i = 0; i < 4; ++i) {
    int q = wid + 4 * i;
    const short* src;
    long base;
    if (q < 8) { src = A; base = (long)(r0 + 16 * q) * K; }
    else       { src = B; base = (long)(o0 + 16 * (q - 8)) * K; }
    gp[i] = src + base + laneoff;
    lp[i] = sm + q * 512;
  }

  f32x4 acc[4][4] = {};
  #pragma unroll
  for (int kc = 0; kc < K; kc += 32) {
    __syncthreads();
    #pragma unroll
    for (int i = 0; i < 4; ++i) {
      GLOAD_LDS(gp[i], lp[i]);
      gp[i] += 32;
    }
    __syncthreads();
    const short8* A8 = (const short8*)sm;
    const short8* B8 = (const short8*)(sm + 4096);
    short8 a[4], b[4];
    #pragma unroll
    for (int m = 0; m < 4; ++m) {
      int row = wm * 64 + m * 16 + lr;
      a[m] = A8[row * 4 + SWZ(row, ls)];
    }
    #pragma unroll
    for (int n = 0; n < 4; ++n) {
      int row = wn * 64 + n * 16 + lr;
      b[n] = B8[row * 4 + SWZ(row, ls)];
    }
    #pragma unroll
    for (int m = 0; m < 4; ++m)
      #pragma unroll
      for (int n = 0; n < 4; ++n)
        acc[m][n] = MFMA16(a[m], b[n], acc[m][n]);
  }
  // ---- argmin epilogue ----
  float cq[4];
  #pragma unroll
  for (int n = 0; n < 4; ++n) cq[n] = cbsq[o0 + wn * 64 + n * 16 + lr];
  #pragma unroll
  for (int m = 0; m < 4; ++m) {
    #pragma unroll
    for (int j = 0; j < 4; ++j) {
      float bv = 3.4e38f; int bi = 0x7fffffff;
      #pragma unroll
      for (int n = 0; n < 4; ++n) {
        int col = o0 + wn * 64 + n * 16 + lr;
        float v = cq[n] - 2.f * acc[m][n][j];
        if (v < bv || (v == bv && col < bi)) { bv = v; bi = col; }
      }
      #pragma unroll
      for (int d = 1; d < 16; d <<= 1) {
        float ov = __shfl_xor(bv, d);
        int oi = __shfl_xor(bi, d);
        if (ov < bv || (ov == bv && oi < bi)) { bv = ov; bi = oi; }
      }
      if (lr == 0) {
        int rl = wm * 64 + m * 16 + ls * 4 + j;
        svv[rl][wn] = bv;
        sii[rl][wn] = bi;
      }
    }
  }
  __syncthreads();
  if (tid < 128) {
    float v0 = svv[tid][0], v1 = svv[tid][1];
    int i0 = sii[tid][0], i1 = sii[tid][1];
    bool t1 = (v1 < v0) || (v1 == v0 && i1 < i0);
    apv[(long)(r0 + tid) * 8 + blockIdx.y] = t1 ? v1 : v0;
    api[(long)(r0 + tid) * 8 + blockIdx.y] = t1 ? i1 : i0;
  }
}

// ================ VQ combine: 8 partials -> argmin; gather + commit ================
__global__ __launch_bounds__(256) void k_vq_combine(const float* __restrict__ apv,
                                                    const int* __restrict__ api,
                                                    const float* __restrict__ ze,
                                                    const float* __restrict__ cb,
                                                    const short* __restrict__ cbkB,
                                                    short* __restrict__ zallB,
                                                    float* __restrict__ commit_part) {
  __shared__ float sv[256];
  __shared__ int ksb;
  int row = blockIdx.x, tid = threadIdx.x;   // row = s*1024 + b*8 + p
  if (tid == 0) {
    float bv = apv[(long)row * 8]; int bi = api[(long)row * 8];
    #pragma unroll
    for (int j = 1; j < 8; ++j) {
      float v = apv[(long)row * 8 + j]; int i = api[(long)row * 8 + j];
      if (v < bv || (v == bv && i < bi)) { bv = v; bi = i; }
    }
    ksb = bi;
  }
  __syncthreads();
  int ks = ksb;
  float zq = cb[ks * 256 + tid];
  float zev = ze[(long)row * 256 + tid];
  int s = row >> 10, bp = row & 1023;
  int b = bp >> 3, p = bp & 7;
  zallB[b * 6144 + s * 2048 + p * 256 + tid] = cbkB[ks * 256 + tid];
  float d = zev - zq;
  sv[tid] = d * d;
  __syncthreads();
  for (int off = 128; off; off >>= 1) { if (tid < off) sv[tid] += sv[tid + off]; __syncthreads(); }
  if (tid == 0) commit_part[row] = sv[0];
}

// ================ bf16 MFMA split-K stage 1: part[bz][M][N] ================
__global__ __launch_bounds__(256) void k_gemm_mfma_sk(const short* __restrict__ A,
                                                      const short* __restrict__ B,
                                                      float* __restrict__ part,
                                                      int M, int N, int K,
                                                      int kchunk, int KS, long bgstride) {
  __shared__ short sm[8192];
  int r0 = blockIdx.x * 128;
  int o0 = blockIdx.y * 128;
  int bz = blockIdx.z;
  int g = bz / KS, zz = bz - g * KS;
  const short* Bg = B + (long)g * bgstride;
  int k0 = zz * kchunk;
  int tid = threadIdx.x;
  int lane = tid & 63, wid = tid >> 6;
  int wm = wid >> 1, wn = wid & 1;
  int ls = lane >> 4, lr = lane & 15;
  int gsl = ((lane & 3) - ((lane >> 3) & 3)) & 3;
  long laneoff = (long)(lane >> 2) * K + gsl * 8 + k0;

  const short* gp[4];
  const short* lp[4];
  #pragma unroll
  for (int i = 0; i < 4; ++i) {
    int q = wid + 4 * i;
    const short* src;
    long base;
    if (q < 8) { src = A;  base = (long)(r0 + 16 * q) * K; }
    else       { src = Bg; base = (long)(o0 + 16 * (q - 8)) * K; }
    gp[i] = src + base + laneoff;
    lp[i] = sm + q * 512;
  }

  f32x4 acc[4][4] = {};
  for (int kc = 0; kc < kchunk; kc += 32) {
    __syncthreads();
    #pragma unroll
    for (int i = 0; i < 4; ++i) {
      GLOAD_LDS(gp[i], lp[i]);
      gp[i] += 32;
    }
    __syncthreads();
    const short8* A8 = (const short8*)sm;
    const short8* B8 = (const short8*)(sm + 4096);
    short8 a[4], b[4];
    #pragma unroll
    for (int m = 0; m < 4; ++m) {
      int row = wm * 64 + m * 16 + lr;
      a[m] = A8[row * 4 + SWZ(row, ls)];
    }
    #pragma unroll
    for (int n = 0; n < 4; ++n) {
      int row = wn * 64 + n * 16 + lr;
      b[n] = B8[row * 4 + SWZ(row, ls)];
    }
    #pragma unroll
    for (int m = 0; m < 4; ++m)
      #pragma unroll
      for (int n = 0; n < 4; ++n)
        acc[m][n] = MFMA16(a[m], b[n], acc[m][n]);
  }
  float* P = part + (long)bz * M * N;
  #pragma unroll
  for (int m = 0; m < 4; ++m) {
    #pragma unroll
    for (int n = 0; n < 4; ++n) {
      int col = o0 + wn * 64 + n * 16 + lr;
      #pragma unroll
      for (int j = 0; j < 4; ++j) {
        int r = r0 + wm * 64 + m * 16 + ls * 4 + j;
        P[(long)r * N + col] = acc[m][n][j];
      }
    }
  }
}

// ================ split-K stage 2 -> bf16 ================
__global__ void k_reduce_bf16(const float* __restrict__ part, short* __restrict__ Cb,
                              const float* __restrict__ bias, int N, int MN,
                              int KS, int relu, int total4) {
  int id = blockIdx.x * 256 + threadIdx.x;
  if (id >= total4) return;
  int e = id * 4;
  int g = e / MN;
  int rem = e - g * MN;
  const float* base = part + (long)g * KS * MN + rem;
  float4 s = *(const float4*)base;
  for (int j = 1; j < KS; ++j) {
    float4 v = *(const float4*)(base + (long)j * MN);
    s.x += v.x; s.y += v.y; s.z += v.z; s.w += v.w;
  }
  int c = rem % N;
  s.x += bias[c]; s.y += bias[c + 1]; s.z += bias[c + 2]; s.w += bias[c + 3];
  if (relu) {
    s.x = fmaxf(s.x, 0.f); s.y = fmaxf(s.y, 0.f);
    s.z = fmaxf(s.z, 0.f); s.w = fmaxf(s.w, 0.f);
  }
  short4v o;
  o[0] = f2bf(s.x); o[1] = f2bf(s.y); o[2] = f2bf(s.z); o[3] = f2bf(s.w);
  *(short4v*)&Cb[(long)g * MN + rem] = o;
}

// ================ adaptive pool: 13 taps, 1/13 each; bf16 in/out ================
__global__ void k_pool(const short* __restrict__ Xg, short* __restrict__ pooledB) {
  int id = blockIdx.x * 256 + threadIdx.x;   // 3072*64 = 196608 exact
  int row = id >> 6, cg = id & 63;
  int s = row >> 10, bp = row & 1023;
  int b = bp >> 3, p = bp & 7;
  int t0 = (p * 25) >> 1;
  const short8* src = (const short8*)(Xg + (long)((s * 128 + b) * TPAD + t0) * 512) + cg;
  float acc[8] = {};
  #pragma unroll
  for (int j = 0; j < 13; ++j) {
    short8 v = src[j * 64];
    #pragma unroll
    for (int k = 0; k < 8; ++k) acc[k] += bf2f(v[k]);
  }
  short8 o;
  #pragma unroll
  for (int k = 0; k < 8; ++k) o[k] = f2bf(acc[k] * (1.f / 13.f));
  ((short8*)pooledB)[(long)row * 64 + cg] = o;
}

// ================ fused: logits-partials reduce + logsumexp + NLL gather ================
__global__ __launch_bounds__(256) void k_logits_lse_recon(const float* __restrict__ part,
                                                          const float* __restrict__ d2b,
                                                          const int* __restrict__ tok,
                                                          float* __restrict__ rpart2) {
  __shared__ float row[1024];
  __shared__ float sm[256];
  int blk = blockIdx.x;
  int cb_i = blk & 3, b = (blk >> 2) & 127, cls = blk >> 9;
  int m = cls * 128 + b;
  const float* p0 = part + (long)m * 4096 + cb_i * 1024;
  const float* p1 = p0 + (long)384 * 4096;
  const float* bb = d2b + cb_i * 1024;
  int tid = threadIdx.x;
  float v[4];
  #pragma unroll
  for (int j = 0; j < 4; ++j) {
    int c = tid + 256 * j;
    v[j] = p0[c] + p1[c] + bb[c];
    row[c] = v[j];
  }
  float mx = fmaxf(fmaxf(v[0], v[1]), fmaxf(v[2], v[3]));
  sm[tid] = mx; __syncthreads();
  for (int off = 128; off; off >>= 1) { if (tid < off) sm[tid] = fmaxf(sm[tid], sm[tid + off]); __syncthreads(); }
  float gm = sm[0]; __syncthreads();
  float e = expf(v[0] - gm) + expf(v[1] - gm) + expf(v[2] - gm) + expf(v[3] - gm);
  sm[tid] = e; __syncthreads();
  for (int off = 128; off; off >>= 1) { if (tid < off) sm[tid] += sm[tid + off]; __syncthreads(); }
  float lse = gm + logf(sm[0]);
  __syncthreads();
  float val = 0.f;
  if (cls == 1) {
    if (tid < 98) {
      int tk = tok[(b * T_ + tid + 1) * CB_ + cb_i];
      val = lse - row[tk];
    }
  } else if (tid == 0) {
    int t = (cls == 0) ? 0 : 99;
    int tk = tok[(b * T_ + t) * CB_ + cb_i];
    val = lse - row[tk];
  }
  sm[tid] = val; __syncthreads();
  for (int off = 128; off; off >>= 1) { if (tid < off) sm[tid] += sm[tid + off]; __syncthreads(); }
  if (tid == 0) rpart2[blk] = sm[0];
}

// ================ final ================
__global__ void k_final(const float* __restrict__ rpart2, const float* __restrict__ cpart,
                        float* __restrict__ out) {
  __shared__ float sm[256];
  __shared__ float rs;
  int tid = threadIdx.x;
  float r = 0.f;
  #pragma unroll
  for (int j = 0; j < 6; ++j) r += rpart2[tid + 256 * j];
  sm[tid] = r; __syncthreads();
  for (int off = 128; off; off >>= 1) { if (tid < off) sm[tid] += sm[tid + off]; __syncthreads(); }
  if (tid == 0) rs = sm[0];
  __syncthreads();
  float c = 0.f;
  #pragma unroll
  for (int j = 0; j < 12; ++j) c += cpart[tid + 256 * j];
  sm[tid] = c; __syncthreads();
  for (int off = 128; off; off >>= 1) { if (tid < off) sm[tid] += sm[tid + off]; __syncthreads(); }
  if (tid == 0) out[0] = rs / 51200.f + 0.1f * (sm[0] / 262144.f);
}

extern "C" void kernel_launch(void* const* d_in, const int* in_sizes, int n_in,
                              void* d_out, int out_size, void* d_ws, size_t ws_size,
                              hipStream_t stream) {
  const int*   tok_prev = (const int*)d_in[0];
  const int*   tok_curr = (const int*)d_in[1];
  const int*   tok_next = (const int*)d_in[2];
  const float* emb  = (const float*)d_in[3];
  const float* c1w  = (const float*)d_in[4];
  const float* c1b  = (const float*)d_in[5];
  const float* c2w  = (const float*)d_in[6];
  const float* c2b  = (const float*)d_in[7];
  const float* c3w  = (const float*)d_in[8];
  const float* c3b  = (const float*)d_in[9];
  const float* cbk  = (const float*)d_in[10];
  const float* fc1w = (const float*)d_in[11];
  const float* fc1b = (const float*)d_in[12];
  const float* fc2w = (const float*)d_in[13];
  const float* fc2b = (const float*)d_in[14];
  const float* d1w  = (const float*)d_in[15];
  const float* d1b  = (const float*)d_in[16];
  const float* d2w  = (const float*)d_in[17];
  const float* d2b  = (const float*)d_in[18];

  // ---- workspace layout (f32 word offsets) ----
  float* ws = (float*)d_ws;
  short* XbS = (short*)ws;                          // conv2 output buffer (bf16)
  short* YbS = (short*)(ws + 10224128);             // conv1 output, guard rows 0 / NROW+1
  float* fp  = ws + 2 * 10224128;
  short* Wb1    = (short*)fp;                       //   393,216 w
  short* Wb2    = (short*)(fp + 393216);            //   393,216 w
  short* c3wB   = (short*)(fp + 786432);            //    65,536 w
  short* cbkB   = (short*)(fp + 851968);            //   131,072 w
  short* pooledB= (short*)(fp + 983040);            //   786,432 w
  float* ze     = fp + 1769472;                     //   786,432 w
  short* zeB    = (short*)(fp + 2555904);           //   393,216 w
  short* fc1wB  = (short*)(fp + 2949120);           // 1,572,864 w
  short* fc2wB  = (short*)(fp + 4521984);           //   131,072 w
  short* SB     = (short*)(fp + 4653056);           //   393,216 w
  short* d2wTB  = (short*)(fp + 5046272);           // 1,048,576 w
  float* part   = fp + 6094848;                     // 3,145,728 w (split-K partials)
  float* cbsq   = part + 3145728;                   //     1,024
  short* zallB  = (short*)(cbsq + 1024);            //   393,216 w
  float* cpart  = cbsq + 1024 + 393216;             //     3,072
  short* h1B    = (short*)(cpart + 3072);           //    32,768 w
  short* h2B    = (short*)(cpart + 35840);          //    32,768 w
  short* h2cB   = (short*)(cpart + 68608);          //    98,304 w
  float* rpart2 = cpart + 166912;                   //     1,536
  float* apv    = cpart + 168448;                   //    24,576
  int*   api    = (int*)(cpart + 193024);           //    24,576
  short* embB   = (short*)(cpart + 217600);         //    65,600 w (131072 + 128 zero-row)
  // total ~30.4M words ~121.5 MB

  const short* Yv = YbS + 512;    // conv1 output rows, row -1 = guard
  short* Xc = XbS + 512;          // conv2 output rows

  // ---- prep ----
  k_prep<<<26885, 256, 0, stream>>>(emb, c1w, c2w, c3w, cbk, fc1w, fc2w, d1w, d2w,
                                    YbS, embB, Wb1, Wb2, c3wB, cbkB, fc1wB, fc2wB,
                                    SB, d2wTB, cbsq);

  // ---- encoder (all 3 segments batched) ----
  k_conv1_embed<<<dim3(4, 312), 256, 0, stream>>>(tok_prev, tok_curr, tok_next,
                                                  embB, Wb1, c1b, (short*)Yv);
  k_conv3_mfma <<<dim3(4, 312), 256, 0, stream>>>(Yv, Wb2, c2b, Xc);
  k_pool       <<<768, 256, 0, stream>>>(Xc, pooledB);
  k_gemm_mfma  <<<dim3(24, 2), 256, 0, stream>>>(pooledB, c3wB, ze, zeB, c3b, 512, 256, 0);
  k_dot_argmin <<<dim3(24, 8), 256, 0, stream>>>(zeB, cbkB, cbsq, apv, api);
  k_vq_combine <<<3072, 256, 0, stream>>>(apv, api, ze, cbk, cbkB, zallB, cpart);

  // ---- decoder: bf16 MFMA split-K ----
  k_gemm_mfma_sk<<<dim3(1, 4, 16), 256, 0, stream>>>(zallB, fc1wB, part, 128, 512, 6144, 384, 16, 0);
  k_reduce_bf16 <<<64, 256, 0, stream>>>(part, h1B, fc1b, 512, 65536, 16, 1, 16384);
  k_gemm_mfma_sk<<<dim3(1, 4, 8), 256, 0, stream>>>(h1B, fc2wB, part, 128, 512, 512, 64, 8, 0);
  k_reduce_bf16 <<<64, 256, 0, stream>>>(part, h2B, fc2b, 512, 65536, 8, 1, 16384);
  k_gemm_mfma_sk<<<dim3(1, 4, 24), 256, 0, stream>>>(h2B, SB, part, 128, 512, 512, 64, 8, 262144);
  k_reduce_bf16 <<<192, 256, 0, stream>>>(part, h2cB, d1b, 512, 65536, 8, 1, 49152);
  k_gemm_mfma_sk<<<dim3(3, 32, 2), 256, 0, stream>>>(h2cB, d2wTB, part, 384, 4096, 512, 256, 2, 0);
  k_logits_lse_recon<<<1536, 256, 0, stream>>>(part, d2b, tok_curr, rpart2);

  k_final<<<1, 256, 0, stream>>>(rpart2, cpart, (float*)d_out);
}

// Round 7
// 261.363 us; speedup vs baseline: 15.7558x; 1.0501x over previous
//
#include <hip/hip_runtime.h>
#include <math.h>

#define B_    128
#define T_    100
#define TPAD  104
#define CB_   4
#define EMB_  128
#define NROW  39936          // 3*128*104 padded rows (all 3 segments)
#define ZOFF  131072         // zero-row offset in embB (shorts)

typedef __attribute__((ext_vector_type(8))) short short8;
typedef __attribute__((ext_vector_type(4))) short short4v;
typedef __attribute__((ext_vector_type(4))) float f32x4;

__device__ __forceinline__ short f2bf(float x) {
  unsigned u = __builtin_bit_cast(unsigned, x);
  u += 0x7fffu + ((u >> 16) & 1u);
  return (short)(u >> 16);
}
__device__ __forceinline__ float bf2f(short s) {
  unsigned u = ((unsigned)(unsigned short)s) << 16;
  return __builtin_bit_cast(float, u);
}

#define GLOAD_LDS(g, l) __builtin_amdgcn_global_load_lds( \
    (const __attribute__((address_space(1))) void*)(g),   \
    (__attribute__((address_space(3))) void*)(l), 16, 0, 0)

#define MFMA16(a, b, c) __builtin_amdgcn_mfma_f32_16x16x32_bf16(a, b, c, 0, 0, 0)
#define SWZ(row, slot) (((slot) + ((row) >> 1)) & 3)

// vmcnt(0) drain + raw barrier + scheduler pin (dbuf step boundary)
#define STEP_SYNC() do {                                   \
    asm volatile("s_waitcnt vmcnt(0)" ::: "memory");       \
    __builtin_amdgcn_s_barrier();                          \
    __builtin_amdgcn_sched_barrier(0);                     \
  } while (0)

// ================ mega-prep: guards + embB + all weight conversions + cbsq ================
__global__ void k_prep(const float* __restrict__ emb,
                       const float* __restrict__ c1w, const float* __restrict__ c2w,
                       const float* __restrict__ c3w, const float* __restrict__ cbk,
                       const float* __restrict__ fc1w, const float* __restrict__ fc2w,
                       const float* __restrict__ d1w, const float* __restrict__ d2w,
                       short* __restrict__ YbS, short* __restrict__ embB,
                       short* __restrict__ Wb1, short* __restrict__ Wb2,
                       short* __restrict__ c3wB, short* __restrict__ cbkB,
                       short* __restrict__ fc1wB, short* __restrict__ fc2wB,
                       short* __restrict__ SB, short* __restrict__ d2wTB,
                       float* __restrict__ cbsq) {
  __shared__ float tile[32][33];
  int bid = blockIdx.x;
  int id = bid * 256 + threadIdx.x;
  if (bid < 24581) {
    if (id < 1024) {
      int row = id >> 9, c = id & 511;
      long off = row ? ((long)(NROW + 1) * 512 + c) : c;
      YbS[off] = 0;
    } else if (id < 132096) {
      int l = id - 1024;
      embB[l] = f2bf(emb[l]);
    } else if (id < 132224) {
      embB[ZOFF + (id - 132096)] = 0;
    } else if (id < 1705088) {
      int local = id - 132224;
      const float* w = (local < 786432) ? c1w : c2w;
      short* o = (local < 786432) ? Wb1 : Wb2;
      int l2 = (local < 786432) ? local : local - 786432;
      int i = l2 & 511, oo = (l2 >> 9) & 511, tap = l2 >> 18;
      o[l2] = f2bf(w[oo * 1536 + i * 3 + tap]);
    } else if (id < 1836160) {
      int l = id - 1705088;
      c3wB[l] = f2bf(c3w[l]);
    } else if (id < 2098304) {
      int l = id - 1836160;
      cbkB[l] = f2bf(cbk[l]);
    } else if (id < 5244032) {
      int l = id - 2098304;
      fc1wB[l] = f2bf(fc1w[l]);
    } else if (id < 5506176) {
      int l = id - 5244032;
      fc2wB[l] = f2bf(fc2w[l]);
    } else if (id < 6292608) {
      int l = id - 5506176;          // 3*512*512
      int i = l & 511, o = (l >> 9) & 511, cls = l >> 18;
      const float* w = d1w + (i * 512 + o) * 3;
      float v;
      if (cls == 0)      v = w[0] + w[1];
      else if (cls == 1) v = w[0] + w[1] + w[2];
      else               v = w[1] + w[2];
      SB[(cls * 512 + o) * 512 + i] = f2bf(v);
    }
  } else if (bid < 26629) {
    int blk = bid - 24581;            // 0..2047
    int bx = blk & 127, by = blk >> 7;
    int tx = threadIdx.x & 31, ty = threadIdx.x >> 5;
    #pragma unroll
    for (int j = 0; j < 32; j += 8)
      tile[ty + j][tx] = d2w[(by * 32 + ty + j) * 4096 + bx * 32 + tx];
    __syncthreads();
    #pragma unroll
    for (int j = 0; j < 32; j += 8)
      d2wTB[(bx * 32 + ty + j) * 512 + by * 32 + tx] = f2bf(tile[tx][ty + j]);
  } else {
    int idx = (bid - 26629) * 256 + threadIdx.x;   // 0..65535
    int row = idx >> 6, lane = threadIdx.x & 63;
    float4 v = *(const float4*)&cbk[row * 256 + lane * 4];
    float s = v.x * v.x + v.y * v.y + v.z * v.z + v.w * v.w;
    #pragma unroll
    for (int m = 1; m < 64; m <<= 1) s += __shfl_xor(s, m);
    if (lane == 0) cbsq[row] = s;
  }
}

// ================ conv1 with fused embedding gather (bf16 MFMA, LDS double-buffered) ================
__global__ __launch_bounds__(256) void k_conv1_embed(const int* __restrict__ tok0,
                                                     const int* __restrict__ tok1,
                                                     const int* __restrict__ tok2,
                                                     const short* __restrict__ embB,
                                                     const short* __restrict__ Wb,
                                                     const float* __restrict__ bias,
                                                     short* __restrict__ Y) {
  __shared__ short sm[2][16896];  // per buf: A 9*16 rows x 32 (4608) + W 24*16 x 32 (12288)
  int r0 = blockIdx.y * 128;
  int o0 = blockIdx.x * 128;
  int tid = threadIdx.x;
  int lane = tid & 63, wid = tid >> 6;
  int wm = wid >> 1, wn = wid & 1;
  int ls = lane >> 4, lr = lane & 15;
  int g = ((lane & 3) - ((lane >> 3) & 3)) & 3;

  // ---- A gather setup: token-derived source offsets per staged row ----
  int toff[3][4];
  #pragma unroll
  for (int i = 0; i < 3; ++i) {
    int q = wid + 4 * i;
    if (q < 9) {
      int rr = r0 - 1 + 16 * q + (lane >> 2);
      bool ok = (rr >= 0) && (rr < NROW);
      int sb = ok ? (rr / 104) : 0;
      int t = rr - sb * 104;
      ok = ok && (t < T_);
      int b = sb & 127, s = sb >> 7;
      const int* tokp = (s == 0) ? tok0 : (s == 1) ? tok1 : tok2;
      if (ok) {
        int4 tv = *(const int4*)&tokp[(b * T_ + t) * CB_];
        toff[i][0] = tv.x * EMB_; toff[i][1] = tv.y * EMB_;
        toff[i][2] = tv.z * EMB_; toff[i][3] = tv.w * EMB_;
      } else {
        toff[i][0] = toff[i][1] = toff[i][2] = toff[i][3] = ZOFF;
      }
    }
  }
  // ---- W pointers (q = 9..32) ----
  const short* gpw[9];
  #pragma unroll
  for (int i = 0; i < 9; ++i) {
    int q = wid + 4 * i;
    if (q >= 9 && q < 33) {
      int b = q - 9, tap = b >> 3, jj = b & 7;
      gpw[i] = Wb + (long)(tap * 512 + o0 + 16 * jj) * 512 + (long)(lane >> 2) * 512 + g * 8;
    }
  }

  // ---- prologue: stage step 0 into buf 0 ----
  #pragma unroll
  for (int i = 0; i < 3; ++i) {
    int q = wid + 4 * i;
    if (q < 9) GLOAD_LDS(embB + toff[i][0] + g * 8, &sm[0][q * 512]);
  }
  #pragma unroll
  for (int i = 0; i < 9; ++i) {
    int q = wid + 4 * i;
    if (q >= 9 && q < 33) { GLOAD_LDS(gpw[i], &sm[0][q * 512]); gpw[i] += 32; }
  }
  STEP_SYNC();

  f32x4 acc[4][4] = {};
  #pragma unroll
  for (int u = 0; u < 16; ++u) {          // u = cb*4 + kk
    const int cur = u & 1;
    if (u < 15) {
      const int cb2 = (u + 1) >> 2, kk2 = (u + 1) & 3;
      #pragma unroll
      for (int i = 0; i < 3; ++i) {
        int q = wid + 4 * i;
        if (q < 9) GLOAD_LDS(embB + toff[i][cb2] + kk2 * 32 + g * 8, &sm[cur ^ 1][q * 512]);
      }
      #pragma unroll
      for (int i = 0; i < 9; ++i) {
        int q = wid + 4 * i;
        if (q >= 9 && q < 33) { GLOAD_LDS(gpw[i], &sm[cur ^ 1][q * 512]); gpw[i] += 32; }
      }
    }
    const short8* A8 = (const short8*)sm[cur];
    const short8* B8 = (const short8*)(sm[cur] + 4608);
    #pragma unroll
    for (int tap = 0; tap < 3; ++tap) {
      short8 a[4], b[4];
      #pragma unroll
      for (int m = 0; m < 4; ++m) {
        int row = wm * 64 + m * 16 + lr + tap;
        a[m] = A8[row * 4 + SWZ(row, ls)];
      }
      #pragma unroll
      for (int n = 0; n < 4; ++n) {
        int row = wn * 64 + n * 16 + lr;
        b[n] = B8[(tap * 128 + row) * 4 + SWZ(row, ls)];
      }
      #pragma unroll
      for (int m = 0; m < 4; ++m)
        #pragma unroll
        for (int n = 0; n < 4; ++n)
          acc[m][n] = MFMA16(a[m], b[n], acc[m][n]);
    }
    STEP_SYNC();
  }
  #pragma unroll
  for (int m = 0; m < 4; ++m) {
    #pragma unroll
    for (int n = 0; n < 4; ++n) {
      int col = o0 + wn * 64 + n * 16 + lr;
      float bv = bias[col];
      #pragma unroll
      for (int j = 0; j < 4; ++j) {
        int r = r0 + wm * 64 + m * 16 + ls * 4 + j;
        int t = r % TPAD;
        float v = (t < T_) ? fmaxf(acc[m][n][j] + bv, 0.f) : 0.f;
        Y[(long)r * 512 + col] = f2bf(v);
      }
    }
  }
}

// ================ 3-tap conv via bf16 MFMA, LDS double-buffered (conv2) ================
__global__ __launch_bounds__(256) void k_conv3_mfma(const short* __restrict__ X,
                                                    const short* __restrict__ Wb,
                                                    const float* __restrict__ bias,
                                                    short* __restrict__ Y) {
  __shared__ short sm[2][16896];
  int r0 = blockIdx.y * 128;
  int o0 = blockIdx.x * 128;
  int tid = threadIdx.x;
  int lane = tid & 63, wid = tid >> 6;
  int wm = wid >> 1, wn = wid & 1;
  int ls = lane >> 4, lr = lane & 15;
  int g = ((lane & 3) - ((lane >> 3) & 3)) & 3;
  long laneoff = (long)(lane >> 2) * 512 + g * 8;

  const short* gp[9];
  #pragma unroll
  for (int i = 0; i < 9; ++i) {
    int q = wid + 4 * i;
    if (q < 33) {
      long base;
      const short* src;
      if (q < 9) { src = X; base = (long)(r0 - 1 + 16 * q) * 512; }
      else {
        int b = q - 9, tap = b >> 3, j = b & 7;
        src = Wb; base = (long)(tap * 512 + o0 + 16 * j) * 512;
      }
      gp[i] = src + base + laneoff;
    }
  }

  // ---- prologue: stage step 0 ----
  #pragma unroll
  for (int i = 0; i < 9; ++i) {
    int q = wid + 4 * i;
    if (q < 33) { GLOAD_LDS(gp[i], &sm[0][q * 512]); gp[i] += 32; }
  }
  STEP_SYNC();

  f32x4 acc[4][4] = {};
  #pragma unroll
  for (int u = 0; u < 16; ++u) {
    const int cur = u & 1;
    if (u < 15) {
      #pragma unroll
      for (int i = 0; i < 9; ++i) {
        int q = wid + 4 * i;
        if (q < 33) { GLOAD_LDS(gp[i], &sm[cur ^ 1][q * 512]); gp[i] += 32; }
      }
    }
    const short8* A8 = (const short8*)sm[cur];
    const short8* B8 = (const short8*)(sm[cur] + 4608);
    #pragma unroll
    for (int tap = 0; tap < 3; ++tap) {
      short8 a[4], b[4];
      #pragma unroll
      for (int m = 0; m < 4; ++m) {
        int row = wm * 64 + m * 16 + lr + tap;
        a[m] = A8[row * 4 + SWZ(row, ls)];
      }
      #pragma unroll
      for (int n = 0; n < 4; ++n) {
        int row = wn * 64 + n * 16 + lr;
        b[n] = B8[(tap * 128 + row) * 4 + SWZ(row, ls)];
      }
      #pragma unroll
      for (int m = 0; m < 4; ++m)
        #pragma unroll
        for (int n = 0; n < 4; ++n)
          acc[m][n] = MFMA16(a[m], b[n], acc[m][n]);
    }
    STEP_SYNC();
  }
  #pragma unroll
  for (int m = 0; m < 4; ++m) {
    #pragma unroll
    for (int n = 0; n < 4; ++n) {
      int col = o0 + wn * 64 + n * 16 + lr;
      float bv = bias[col];
      #pragma unroll
      for (int j = 0; j < 4; ++j) {
        int r = r0 + wm * 64 + m * 16 + ls * 4 + j;
        int t = r % TPAD;
        float v = (t < T_) ? fmaxf(acc[m][n][j] + bv, 0.f) : 0.f;
        Y[(long)r * 512 + col] = f2bf(v);
      }
    }
  }
}

// ================ bf16 MFMA GEMM (full-K): C = act(A@B^T + bias) ================
__global__ __launch_bounds__(256) void k_gemm_mfma(const short* __restrict__ A,
                                                   const short* __restrict__ B,
                                                   float* __restrict__ C,
                                                   short* __restrict__ Cb,
                                                   const float* __restrict__ bias,
                                                   int K, int N, int relu) {
  __shared__ short sm[8192];
  int r0 = blockIdx.x * 128;
  int o0 = blockIdx.y * 128;
  int tid = threadIdx.x;
  int lane = tid & 63, wid = tid >> 6;
  int wm = wid >> 1, wn = wid & 1;
  int ls = lane >> 4, lr = lane & 15;
  int g = ((lane & 3) - ((lane >> 3) & 3)) & 3;
  long laneoff = (long)(lane >> 2) * K + g * 8;

  const short* gp[4];
  const short* lp[4];
  #pragma unroll
  for (int i = 0; i < 4; ++i) {
    int q = wid + 4 * i;
    const short* src;
    long base;
    if (q < 8) { src = A; base = (long)(r0 + 16 * q) * K; }
    else       { src = B; base = (long)(o0 + 16 * (q - 8)) * K; }
    gp[i] = src + base + laneoff;
    lp[i] = sm + q * 512;
  }

  f32x4 acc[4][4] = {};
  for (int kc = 0; kc < K; kc += 32) {
    __syncthreads();
    #pragma unroll
    for (int i = 0; i < 4; ++i) {
      GLOAD_LDS(gp[i], lp[i]);
      gp[i] += 32;
    }
    __syncthreads();
    const short8* A8 = (const short8*)sm;
    const short8* B8 = (const short8*)(sm + 4096);
    short8 a[4], b[4];
    #pragma unroll
    for (int m = 0; m < 4; ++m) {
      int row = wm * 64 + m * 16 + lr;
      a[m] = A8[row * 4 + SWZ(row, ls)];
    }
    #pragma unroll
    for (int n = 0; n < 4; ++n) {
      int row = wn * 64 + n * 16 + lr;
      b[n] = B8[row * 4 + SWZ(row, ls)];
    }
    #pragma unroll
    for (int m = 0; m < 4; ++m)
      #pragma unroll
      for (int n = 0; n < 4; ++n)
        acc[m][n] = MFMA16(a[m], b[n], acc[m][n]);
  }
  #pragma unroll
  for (int m = 0; m < 4; ++m) {
    #pragma unroll
    for (int n = 0; n < 4; ++n) {
      int col = o0 + wn * 64 + n * 16 + lr;
      float bv = bias ? bias[col] : 0.f;
      #pragma unroll
      for (int j = 0; j < 4; ++j) {
        int r = r0 + wm * 64 + m * 16 + ls * 4 + j;
        float v = acc[m][n][j] + bv;
        if (relu) v = fmaxf(v, 0.f);
        C[(long)r * N + col] = v;
        if (Cb) Cb[(long)r * N + col] = f2bf(v);
      }
    }
  }
}

// ================ dot GEMM + per-tile argmin partials (fused) ================
__global__ __launch_bounds__(256) void k_dot_argmin(const short* __restrict__ A,
                                                    const short* __restrict__ B,
                                                    const float* __restrict__ cbsq,
                                                    float* __restrict__ apv,
                                                    int* __restrict__ api) {
  __shared__ short sm[8192];
  __shared__ float svv[128][2];
  __shared__ int sii[128][2];
  const int K = 256;
  int r0 = blockIdx.x * 128;
  int o0 = blockIdx.y * 128;
  int tid = threadIdx.x;
  int lane = tid & 63, wid = tid >> 6;
  int wm = wid >> 1, wn = wid & 1;
  int ls = lane >> 4, lr = lane & 15;
  int g = ((lane & 3) - ((lane >> 3) & 3)) & 3;
  long laneoff = (long)(lane >> 2) * K + g * 8;

  const short* gp[4];
  const short* lp[4];
  #pragma unroll
  for (int i = 0; i < 4; ++i) {
    int q = wid + 4 * i;
    const short* src;
    long base;
    if (q < 8) { src = A; base = (long)(r0 + 16 * q) * K; }
    else       { src = B; base = (long)(o0 + 16 * (q - 8)) * K; }
    gp[i] = src + base + laneoff;
    lp[i] = sm + q * 512;
  }

  f32x4 acc[4][4] = {};
  #pragma unroll
  for (int kc = 0; kc < K; kc += 32) {
    __syncthreads();
    #pragma unroll
    for (int i = 0; i < 4; ++i) {
      GLOAD_LDS(gp[i], lp[i]);
      gp[i] += 32;
    }
    __syncthreads();
    const short8* A8 = (const short8*)sm;
    const short8* B8 = (const short8*)(sm + 4096);
    short8 a[4], b[4];
    #pragma unroll
    for (int m = 0; m < 4; ++m) {
      int row = wm * 64 + m * 16 + lr;
      a[m] = A8[row * 4 + SWZ(row, ls)];
    }
    #pragma unroll
    for (int n = 0; n < 4; ++n) {
      int row = wn * 64 + n * 16 + lr;
      b[n] = B8[row * 4 + SWZ(row, ls)];
    }
    #pragma unroll
    for (int m = 0; m < 4; ++m)
      #pragma unroll
      for (int n = 0; n < 4; ++n)
        acc[m][n] = MFMA16(a[m], b[n], acc[m][n]);
  }
  // ---- argmin epilogue ----
  float cq[4];
  #pragma unroll
  for (int n = 0; n < 4; ++n) cq[n] = cbsq[o0 + wn * 64 + n * 16 + lr];
  #pragma unroll
  for (int m = 0; m < 4; ++m) {
    #pragma unroll
    for (int j = 0; j < 4; ++j) {
      float bv = 3.4e38f; int bi = 0x7fffffff;
      #pragma unroll
      for (int n = 0; n < 4; ++n) {
        int col = o0 + wn * 64 + n * 16 + lr;
        float v = cq[n] - 2.f * acc[m][n][j];
        if (v < bv || (v == bv && col < bi)) { bv = v; bi = col; }
      }
      #pragma unroll
      for (int d = 1; d < 16; d <<= 1) {
        float ov = __shfl_xor(bv, d);
        int oi = __shfl_xor(bi, d);
        if (ov < bv || (ov == bv && oi < bi)) { bv = ov; bi = oi; }
      }
      if (lr == 0) {
        int rl = wm * 64 + m * 16 + ls * 4 + j;
        svv[rl][wn] = bv;
        sii[rl][wn] = bi;
      }
    }
  }
  __syncthreads();
  if (tid < 128) {
    float v0 = svv[tid][0], v1 = svv[tid][1];
    int i0 = sii[tid][0], i1 = sii[tid][1];
    bool t1 = (v1 < v0) || (v1 == v0 && i1 < i0);
    apv[(long)(r0 + tid) * 8 + blockIdx.y] = t1 ? v1 : v0;
    api[(long)(r0 + tid) * 8 + blockIdx.y] = t1 ? i1 : i0;
  }
}

// ================ VQ combine: 8 partials -> argmin; gather + commit ================
__global__ __launch_bounds__(256) void k_vq_combine(const float* __restrict__ apv,
                                                    const int* __restrict__ api,
                                                    const float* __restrict__ ze,
                                                    const float* __restrict__ cb,
                                                    const short* __restrict__ cbkB,
                                                    short* __restrict__ zallB,
                                                    float* __restrict__ commit_part) {
  __shared__ float sv[256];
  __shared__ int ksb;
  int row = blockIdx.x, tid = threadIdx.x;   // row = s*1024 + b*8 + p
  if (tid == 0) {
    float bv = apv[(long)row * 8]; int bi = api[(long)row * 8];
    #pragma unroll
    for (int j = 1; j < 8; ++j) {
      float v = apv[(long)row * 8 + j]; int i = api[(long)row * 8 + j];
      if (v < bv || (v == bv && i < bi)) { bv = v; bi = i; }
    }
    ksb = bi;
  }
  __syncthreads();
  int ks = ksb;
  float zq = cb[ks * 256 + tid];
  float zev = ze[(long)row * 256 + tid];
  int s = row >> 10, bp = row & 1023;
  int b = bp >> 3, p = bp & 7;
  zallB[b * 6144 + s * 2048 + p * 256 + tid] = cbkB[ks * 256 + tid];
  float d = zev - zq;
  sv[tid] = d * d;
  __syncthreads();
  for (int off = 128; off; off >>= 1) { if (tid < off) sv[tid] += sv[tid + off]; __syncthreads(); }
  if (tid == 0) commit_part[row] = sv[0];
}

// ================ bf16 MFMA split-K stage 1: part[bz][M][N] ================
__global__ __launch_bounds__(256) void k_gemm_mfma_sk(const short* __restrict__ A,
                                                      const short* __restrict__ B,
                                                      float* __restrict__ part,
                                                      int M, int N, int K,
                                                      int kchunk, int KS, long bgstride) {
  __shared__ short sm[8192];
  int r0 = blockIdx.x * 128;
  int o0 = blockIdx.y * 128;
  int bz = blockIdx.z;
  int g = bz / KS, zz = bz - g * KS;
  const short* Bg = B + (long)g * bgstride;
  int k0 = zz * kchunk;
  int tid = threadIdx.x;
  int lane = tid & 63, wid = tid >> 6;
  int wm = wid >> 1, wn = wid & 1;
  int ls = lane >> 4, lr = lane & 15;
  int gsl = ((lane & 3) - ((lane >> 3) & 3)) & 3;
  long laneoff = (long)(lane >> 2) * K + gsl * 8 + k0;

  const short* gp[4];
  const short* lp[4];
  #pragma unroll
  for (int i = 0; i < 4; ++i) {
    int q = wid + 4 * i;
    const short* src;
    long base;
    if (q < 8) { src = A;  base = (long)(r0 + 16 * q) * K; }
    else       { src = Bg; base = (long)(o0 + 16 * (q - 8)) * K; }
    gp[i] = src + base + laneoff;
    lp[i] = sm + q * 512;
  }

  f32x4 acc[4][4] = {};
  for (int kc = 0; kc < kchunk; kc += 32) {
    __syncthreads();
    #pragma unroll
    for (int i = 0; i < 4; ++i) {
      GLOAD_LDS(gp[i], lp[i]);
      gp[i] += 32;
    }
    __syncthreads();
    const short8* A8 = (const short8*)sm;
    const short8* B8 = (const short8*)(sm + 4096);
    short8 a[4], b[4];
    #pragma unroll
    for (int m = 0; m < 4; ++m) {
      int row = wm * 64 + m * 16 + lr;
      a[m] = A8[row * 4 + SWZ(row, ls)];
    }
    #pragma unroll
    for (int n = 0; n < 4; ++n) {
      int row = wn * 64 + n * 16 + lr;
      b[n] = B8[row * 4 + SWZ(row, ls)];
    }
    #pragma unroll
    for (int m = 0; m < 4; ++m)
      #pragma unroll
      for (int n = 0; n < 4; ++n)
        acc[m][n] = MFMA16(a[m], b[n], acc[m][n]);
  }
  float* P = part + (long)bz * M * N;
  #pragma unroll
  for (int m = 0; m < 4; ++m) {
    #pragma unroll
    for (int n = 0; n < 4; ++n) {
      int col = o0 + wn * 64 + n * 16 + lr;
      #pragma unroll
      for (int j = 0; j < 4; ++j) {
        int r = r0 + wm * 64 + m * 16 + ls * 4 + j;
        P[(long)r * N + col] = acc[m][n][j];
      }
    }
  }
}

// ================ split-K stage 2 -> bf16 ================
__global__ void k_reduce_bf16(const float* __restrict__ part, short* __restrict__ Cb,
                              const float* __restrict__ bias, int N, int MN,
                              int KS, int relu, int total4) {
  int id = blockIdx.x * 256 + threadIdx.x;
  if (id >= total4) return;
  int e = id * 4;
  int g = e / MN;
  int rem = e - g * MN;
  const float* base = part + (long)g * KS * MN + rem;
  float4 s = *(const float4*)base;
  for (int j = 1; j < KS; ++j) {
    float4 v = *(const float4*)(base + (long)j * MN);
    s.x += v.x; s.y += v.y; s.z += v.z; s.w += v.w;
  }
  int c = rem % N;
  s.x += bias[c]; s.y += bias[c + 1]; s.z += bias[c + 2]; s.w += bias[c + 3];
  if (relu) {
    s.x = fmaxf(s.x, 0.f); s.y = fmaxf(s.y, 0.f);
    s.z = fmaxf(s.z, 0.f); s.w = fmaxf(s.w, 0.f);
  }
  short4v o;
  o[0] = f2bf(s.x); o[1] = f2bf(s.y); o[2] = f2bf(s.z); o[3] = f2bf(s.w);
  *(short4v*)&Cb[(long)g * MN + rem] = o;
}

// ================ adaptive pool: 13 taps, 1/13 each; bf16 in/out ================
__global__ void k_pool(const short* __restrict__ Xg, short* __restrict__ pooledB) {
  int id = blockIdx.x * 256 + threadIdx.x;   // 3072*64 = 196608 exact
  int row = id >> 6, cg = id & 63;
  int s = row >> 10, bp = row & 1023;
  int b = bp >> 3, p = bp & 7;
  int t0 = (p * 25) >> 1;
  const short8* src = (const short8*)(Xg + (long)((s * 128 + b) * TPAD + t0) * 512) + cg;
  float acc[8] = {};
  #pragma unroll
  for (int j = 0; j < 13; ++j) {
    short8 v = src[j * 64];
    #pragma unroll
    for (int k = 0; k < 8; ++k) acc[k] += bf2f(v[k]);
  }
  short8 o;
  #pragma unroll
  for (int k = 0; k < 8; ++k) o[k] = f2bf(acc[k] * (1.f / 13.f));
  ((short8*)pooledB)[(long)row * 64 + cg] = o;
}

// ================ fused: logits-partials reduce + logsumexp + NLL gather ================
__global__ __launch_bounds__(256) void k_logits_lse_recon(const float* __restrict__ part,
                                                          const float* __restrict__ d2b,
                                                          const int* __restrict__ tok,
                                                          float* __restrict__ rpart2) {
  __shared__ float row[1024];
  __shared__ float sm[256];
  int blk = blockIdx.x;
  int cb_i = blk & 3, b = (blk >> 2) & 127, cls = blk >> 9;
  int m = cls * 128 + b;
  const float* p0 = part + (long)m * 4096 + cb_i * 1024;
  const float* p1 = p0 + (long)384 * 4096;
  const float* bb = d2b + cb_i * 1024;
  int tid = threadIdx.x;
  float v[4];
  #pragma unroll
  for (int j = 0; j < 4; ++j) {
    int c = tid + 256 * j;
    v[j] = p0[c] + p1[c] + bb[c];
    row[c] = v[j];
  }
  float mx = fmaxf(fmaxf(v[0], v[1]), fmaxf(v[2], v[3]));
  sm[tid] = mx; __syncthreads();
  for (int off = 128; off; off >>= 1) { if (tid < off) sm[tid] = fmaxf(sm[tid], sm[tid + off]); __syncthreads(); }
  float gm = sm[0]; __syncthreads();
  float e = expf(v[0] - gm) + expf(v[1] - gm) + expf(v[2] - gm) + expf(v[3] - gm);
  sm[tid] = e; __syncthreads();
  for (int off = 128; off; off >>= 1) { if (tid < off) sm[tid] += sm[tid + off]; __syncthreads(); }
  float lse = gm + logf(sm[0]);
  __syncthreads();
  float val = 0.f;
  if (cls == 1) {
    if (tid < 98) {
      int tk = tok[(b * T_ + tid + 1) * CB_ + cb_i];
      val = lse - row[tk];
    }
  } else if (tid == 0) {
    int t = (cls == 0) ? 0 : 99;
    int tk = tok[(b * T_ + t) * CB_ + cb_i];
    val = lse - row[tk];
  }
  sm[tid] = val; __syncthreads();
  for (int off = 128; off; off >>= 1) { if (tid < off) sm[tid] += sm[tid + off]; __syncthreads(); }
  if (tid == 0) rpart2[blk] = sm[0];
}

// ================ final ================
__global__ void k_final(const float* __restrict__ rpart2, const float* __restrict__ cpart,
                        float* __restrict__ out) {
  __shared__ float sm[256];
  __shared__ float rs;
  int tid = threadIdx.x;
  float r = 0.f;
  #pragma unroll
  for (int j = 0; j < 6; ++j) r += rpart2[tid + 256 * j];
  sm[tid] = r; __syncthreads();
  for (int off = 128; off; off >>= 1) { if (tid < off) sm[tid] += sm[tid + off]; __syncthreads(); }
  if (tid == 0) rs = sm[0];
  __syncthreads();
  float c = 0.f;
  #pragma unroll
  for (int j = 0; j < 12; ++j) c += cpart[tid + 256 * j];
  sm[tid] = c; __syncthreads();
  for (int off = 128; off; off >>= 1) { if (tid < off) sm[tid] += sm[tid + off]; __syncthreads(); }
  if (tid == 0) out[0] = rs / 51200.f + 0.1f * (sm[0] / 262144.f);
}

extern "C" void kernel_launch(void* const* d_in, const int* in_sizes, int n_in,
                              void* d_out, int out_size, void* d_ws, size_t ws_size,
                              hipStream_t stream) {
  const int*   tok_prev = (const int*)d_in[0];
  const int*   tok_curr = (const int*)d_in[1];
  const int*   tok_next = (const int*)d_in[2];
  const float* emb  = (const float*)d_in[3];
  const float* c1w  = (const float*)d_in[4];
  const float* c1b  = (const float*)d_in[5];
  const float* c2w  = (const float*)d_in[6];
  const float* c2b  = (const float*)d_in[7];
  const float* c3w  = (const float*)d_in[8];
  const float* c3b  = (const float*)d_in[9];
  const float* cbk  = (const float*)d_in[10];
  const float* fc1w = (const float*)d_in[11];
  const float* fc1b = (const float*)d_in[12];
  const float* fc2w = (const float*)d_in[13];
  const float* fc2b = (const float*)d_in[14];
  const float* d1w  = (const float*)d_in[15];
  const float* d1b  = (const float*)d_in[16];
  const float* d2w  = (const float*)d_in[17];
  const float* d2b  = (const float*)d_in[18];

  // ---- workspace layout (f32 word offsets) ----
  float* ws = (float*)d_ws;
  short* XbS = (short*)ws;                          // conv2 output buffer (bf16)
  short* YbS = (short*)(ws + 10224128);             // conv1 output, guard rows 0 / NROW+1
  float* fp  = ws + 2 * 10224128;
  short* Wb1    = (short*)fp;                       //   393,216 w
  short* Wb2    = (short*)(fp + 393216);            //   393,216 w
  short* c3wB   = (short*)(fp + 786432);            //    65,536 w
  short* cbkB   = (short*)(fp + 851968);            //   131,072 w
  short* pooledB= (short*)(fp + 983040);            //   786,432 w
  float* ze     = fp + 1769472;                     //   786,432 w
  short* zeB    = (short*)(fp + 2555904);           //   393,216 w
  short* fc1wB  = (short*)(fp + 2949120);           // 1,572,864 w
  short* fc2wB  = (short*)(fp + 4521984);           //   131,072 w
  short* SB     = (short*)(fp + 4653056);           //   393,216 w
  short* d2wTB  = (short*)(fp + 5046272);           // 1,048,576 w
  float* part   = fp + 6094848;                     // 3,145,728 w (split-K partials)
  float* cbsq   = part + 3145728;                   //     1,024
  short* zallB  = (short*)(cbsq + 1024);            //   393,216 w
  float* cpart  = cbsq + 1024 + 393216;             //     3,072
  short* h1B    = (short*)(cpart + 3072);           //    32,768 w
  short* h2B    = (short*)(cpart + 35840);          //    32,768 w
  short* h2cB   = (short*)(cpart + 68608);          //    98,304 w
  float* rpart2 = cpart + 166912;                   //     1,536
  float* apv    = cpart + 168448;                   //    24,576
  int*   api    = (int*)(cpart + 193024);           //    24,576
  short* embB   = (short*)(cpart + 217600);         //    65,600 w (131072 + 128 zero-row)
  // total ~30.4M words ~121.5 MB

  const short* Yv = YbS + 512;    // conv1 output rows, row -1 = guard
  short* Xc = XbS + 512;          // conv2 output rows

  // ---- prep ----
  k_prep<<<26885, 256, 0, stream>>>(emb, c1w, c2w, c3w, cbk, fc1w, fc2w, d1w, d2w,
                                    YbS, embB, Wb1, Wb2, c3wB, cbkB, fc1wB, fc2wB,
                                    SB, d2wTB, cbsq);

  // ---- encoder (all 3 segments batched) ----
  k_conv1_embed<<<dim3(4, 312), 256, 0, stream>>>(tok_prev, tok_curr, tok_next,
                                                  embB, Wb1, c1b, (short*)Yv);
  k_conv3_mfma <<<dim3(4, 312), 256, 0, stream>>>(Yv, Wb2, c2b, Xc);
  k_pool       <<<768, 256, 0, stream>>>(Xc, pooledB);
  k_gemm_mfma  <<<dim3(24, 2), 256, 0, stream>>>(pooledB, c3wB, ze, zeB, c3b, 512, 256, 0);
  k_dot_argmin <<<dim3(24, 8), 256, 0, stream>>>(zeB, cbkB, cbsq, apv, api);
  k_vq_combine <<<3072, 256, 0, stream>>>(apv, api, ze, cbk, cbkB, zallB, cpart);

  // ---- decoder: bf16 MFMA split-K ----
  k_gemm_mfma_sk<<<dim3(1, 4, 16), 256, 0, stream>>>(zallB, fc1wB, part, 128, 512, 6144, 384, 16, 0);
  k_reduce_bf16 <<<64, 256, 0, stream>>>(part, h1B, fc1b, 512, 65536, 16, 1, 16384);
  k_gemm_mfma_sk<<<dim3(1, 4, 8), 256, 0, stream>>>(h1B, fc2wB, part, 128, 512, 512, 64, 8, 0);
  k_reduce_bf16 <<<64, 256, 0, stream>>>(part, h2B, fc2b, 512, 65536, 8, 1, 16384);
  k_gemm_mfma_sk<<<dim3(1, 4, 24), 256, 0, stream>>>(h2B, SB, part, 128, 512, 512, 64, 8, 262144);
  k_reduce_bf16 <<<192, 256, 0, stream>>>(part, h2cB, d1b, 512, 65536, 8, 1, 49152);
  k_gemm_mfma_sk<<<dim3(3, 32, 2), 256, 0, stream>>>(h2cB, d2wTB, part, 384, 4096, 512, 256, 2, 0);
  k_logits_lse_recon<<<1536, 256, 0, stream>>>(part, d2b, tok_curr, rpart2);

  k_final<<<1, 256, 0, stream>>>(rpart2, cpart, (float*)d_out);
}